// Round 1
// baseline (1133.612 us; speedup 1.0000x reference)
//
#include <hip/hip_runtime.h>
#include <hip/hip_bf16.h>

#define NPTS 692736      // 24*41*16*44
#define NPATCH 16896     // 24*16*44

// ---------- module-scope device globals ----------
__device__ float  v11_xbuf[NPATCH*256];
__device__ float  v11_ctx[NPATCH*64];
__device__ float  v11_depth[NPATCH*41];
__device__ int    v11_ranks[NPTS];
__device__ float  v11_bev[16384*64];
__device__ float  v11_w2[64*64*9];
__device__ float  v11_wT[768*256];     // conv_w transposed to [k][o]
__device__ double v11_geom[24*24];

// counting-sort state for scatter->gather inversion
__device__ int    v12_cnt[16384];
__device__ int    v12_off[16384];
__device__ int    v12_cur[16384];
__device__ int    v12_sorted[NPTS];    // packed (p<<6)|d in rank order

__device__ __forceinline__ void inv3_v11(const double* m, double* o){
  double a=m[0],b=m[1],c=m[2],d=m[3],e=m[4],f=m[5],g=m[6],h=m[7],i=m[8];
  double A = e*i - f*h, B = -(d*i - f*g), C = d*h - e*g;
  double det = a*A + b*B + c*C;
  double id = 1.0/det;
  o[0]=A*id;            o[1]=-(b*i - c*h)*id; o[2]=(b*f - c*e)*id;
  o[3]=B*id;            o[4]=(a*i - c*g)*id;  o[5]=-(a*f - c*d)*id;
  o[6]=C*id;            o[7]=-(a*h - b*g)*id; o[8]=(a*e - b*d)*id;
}

__global__ void zerocnt_v12(){
  v12_cnt[blockIdx.x*256 + threadIdx.x] = 0;
}

__global__ void geom_v11(const float* rots, const float* trans, const float* intrins,
                         const float* post_rots, const float* post_trans){
  int t = threadIdx.x;
  if (t >= 24) return;
  double pr[9], it[9], r[9];
  for (int i=0;i<9;i++){
    pr[i] = (double)post_rots[t*9+i];
    it[i] = (double)intrins[t*9+i];
    r[i]  = (double)rots[t*9+i];
  }
  double ipr[9], iit[9];
  inv3_v11(pr, ipr); inv3_v11(it, iit);
  double* g = v11_geom + t*24;
  for (int i=0;i<3;i++) for(int j=0;j<3;j++){
    double s=0; for(int k=0;k<3;k++) s += r[i*3+k]*iit[k*3+j];
    g[9+i*3+j]=s;
  }
  for (int i=0;i<9;i++) g[i]   = ipr[i];
  for (int i=0;i<3;i++) g[18+i]= (double)post_trans[t*3+i];
  for (int i=0;i<3;i++) g[21+i]= (double)trans[t*3+i];
}

// transpose conv_w [256 o][768 k] -> wT [768 k][256 o]
__global__ void wt_v11(const float* cw){
  int gid = blockIdx.x*256 + threadIdx.x;   // 196608
  int k = gid >> 8, o = gid & 255;
  v11_wT[gid] = cw[o*768 + k];
}

// conv1 as register-blocked GEMM: block = 32 patches x 256 ch, thread = 8pp x 4ch
__global__ __launch_bounds__(256) void conv1_v11(const float* img,
    const float* cb, const float* g1, const float* b1, const float* m1, const float* v1){
  __shared__ float sp[32*36];    // [kk][pp], stride 36 (16B-aligned, bank-spread)
  __shared__ float sw[32*256];   // [kk][ch]
  int tid = threadIdx.x;
  int cg = tid & 63;             // 64 ch-groups x 4ch
  int pg = tid >> 6;             // 4 patch-groups x 8pp
  int pbase = blockIdx.x*32;
  int im = pbase/704;            // 704 % 32 == 0: all patches same image

  float acc[4][8];
  #pragma unroll
  for (int j=0;j<4;j++)
    #pragma unroll
    for (int i=0;i<8;i++) acc[j][i]=0.f;

  for (int kt=0; kt<768; kt+=32){
    __syncthreads();
    // stage weights (coalesced from transposed wT)
    for (int l = tid; l < 8192; l += 256)
      sw[l] = v11_wT[(kt + (l>>8))*256 + (l&255)];
    // stage patches
    for (int l = tid; l < 1024; l += 256){
      int kk = l>>5, pp = l&31;
      int k = kt + kk;
      int p = pbase + pp;
      int pix = p % 704;
      int ph = pix/44, pw = pix%44;
      int c = k>>8, rem = k&255, ky = rem>>4, kx = rem&15;
      sp[kk*36+pp] = img[(size_t)im*540672 + (size_t)c*180224 +
                         (size_t)(ph*16+ky)*704 + (pw*16+kx)];
    }
    __syncthreads();
    #pragma unroll 8
    for (int kk=0; kk<32; kk++){
      float4 p0 = *(const float4*)&sp[kk*36 + pg*8];
      float4 p1 = *(const float4*)&sp[kk*36 + pg*8 + 4];
      float4 wv = *(const float4*)&sw[kk*256 + cg*4];
      float pv[8] = {p0.x,p0.y,p0.z,p0.w,p1.x,p1.y,p1.z,p1.w};
      float wa[4] = {wv.x,wv.y,wv.z,wv.w};
      #pragma unroll
      for (int j=0;j<4;j++)
        #pragma unroll
        for (int i=0;i<8;i++) acc[j][i] += wa[j]*pv[i];
    }
  }
  // BN + ReLU epilogue, coalesced float4 stores
  float sc[4], sh[4], bi[4];
  #pragma unroll
  for (int j=0;j<4;j++){
    int ch = cg*4+j;
    sc[j] = g1[ch] / sqrtf(v1[ch] + 1e-5f);
    sh[j] = b1[ch] - m1[ch]*sc[j];
    bi[j] = cb[ch];
  }
  #pragma unroll
  for (int i=0;i<8;i++){
    int p = pbase + pg*8 + i;
    float4 v;
    float t0 = (acc[0][i]+bi[0])*sc[0] + sh[0]; v.x = t0>0.f?t0:0.f;
    float t1 = (acc[1][i]+bi[1])*sc[1] + sh[1]; v.y = t1>0.f?t1:0.f;
    float t2 = (acc[2][i]+bi[2])*sc[2] + sh[2]; v.z = t2>0.f?t2:0.f;
    float t3 = (acc[3][i]+bi[3])*sc[3] + sh[3]; v.w = t3>0.f?t3:0.f;
    *(float4*)&v11_xbuf[(size_t)p*256 + cg*4] = v;
  }
}

// depth head as blocked GEMM + softmax + ctx split: block = 32 patches
__global__ __launch_bounds__(256) void depth_v11(const float* dw, const float* db){
  __shared__ float sx[32*260];    // [pp][c], stride 260 (33,280 B)
  __shared__ float sdw[105*36];   // [o][c-chunk 32], stride 36 (15,120 B)
  __shared__ float sy[32*112];    // [pp][o] accum (14,336 B)
  int tid = threadIdx.x;
  int pbase = blockIdx.x*32;
  // load x tile
  for (int l = tid; l < 8192; l += 256){
    int pp = l>>8, c = l&255;
    sx[pp*260+c] = v11_xbuf[(size_t)(pbase+pp)*256 + c];
  }
  // init y with bias
  for (int l = tid; l < 32*105; l += 256){
    int pp = l/105, o = l%105;
    sy[pp*112+o] = db[o];
  }
  int ppg = tid >> 4;   // 16 groups x 2 pp
  int og  = tid & 15;   // 16 groups x 7 o
  for (int ch = 0; ch < 8; ch++){       // 8 chunks of 32 c
    __syncthreads();
    for (int l = tid; l < 105*32; l += 256){
      int o = l>>5, c = l&31;
      sdw[o*36+c] = dw[o*256 + ch*32 + c];
    }
    __syncthreads();
    float a0[7], a1[7];
    #pragma unroll
    for (int oj=0;oj<7;oj++){ a0[oj]=0.f; a1[oj]=0.f; }
    const float* x0 = &sx[(ppg*2  )*260 + ch*32];
    const float* x1 = &sx[(ppg*2+1)*260 + ch*32];
    #pragma unroll
    for (int c4=0; c4<8; c4++){
      float4 xa = *(const float4*)&x0[c4*4];
      float4 xb = *(const float4*)&x1[c4*4];
      #pragma unroll
      for (int oj=0;oj<7;oj++){
        int o = og*7+oj;
        if (o < 105){
          float4 wv = *(const float4*)&sdw[o*36 + c4*4];
          a0[oj] += xa.x*wv.x + xa.y*wv.y + xa.z*wv.z + xa.w*wv.w;
          a1[oj] += xb.x*wv.x + xb.y*wv.y + xb.z*wv.z + xb.w*wv.w;
        }
      }
    }
    #pragma unroll
    for (int oj=0;oj<7;oj++){
      int o = og*7+oj;
      if (o < 105){
        sy[(ppg*2  )*112+o] += a0[oj];
        sy[(ppg*2+1)*112+o] += a1[oj];
      }
    }
  }
  __syncthreads();
  // softmax over first 41 per patch (32 threads)
  if (tid < 32){
    float* y = &sy[tid*112];
    float m = y[0];
    for (int i=1;i<41;i++) m = fmaxf(m, y[i]);
    float s = 0.f;
    for (int i=0;i<41;i++){ float e = expf(y[i]-m); y[i] = e; s += e; }
    float inv = 1.f/s;
    for (int i=0;i<41;i++) y[i] *= inv;
  }
  __syncthreads();
  // write depth + ctx (coalesced)
  for (int l = tid; l < 32*41; l += 256){
    int pp = l/41, dd = l%41;
    v11_depth[(size_t)(pbase+pp)*41 + dd] = sy[pp*112+dd];
  }
  for (int l = tid; l < 32*64; l += 256){
    int pp = l>>6, c = l&63;
    v11_ctx[(size_t)(pbase+pp)*64 + c] = sy[pp*112 + 41 + c];
  }
}

// voxel rank per frustum point (trunc-toward-zero, rank aliasing allowed)
// now also builds the per-voxel histogram for the counting sort
__global__ __launch_bounds__(256) void rank_v11(){
  int idx = blockIdx.x*256 + threadIdx.x;
  if (idx >= NPTS) return;
  int im = idx / 28864;
  int r  = idx % 28864;
  int d  = r / 704; int pix = r % 704;
  int h = pix / 44, w = pix % 44;
  const double* g = v11_geom + im*24;
  double fx = (double)w * (703.0/43.0);
  double fy = (double)h * 17.0;
  double fz = 4.0 + (double)d;
  double px = fx - g[18], py = fy - g[19], pz = fz - g[20];
  double q0 = g[0]*px + g[1]*py + g[2]*pz;
  double q1 = g[3]*px + g[4]*py + g[5]*pz;
  double q2 = g[6]*px + g[7]*py + g[8]*pz;
  q0 *= q2; q1 *= q2;
  double o0 = g[9]*q0  + g[10]*q1 + g[11]*q2 + g[21];
  double o1 = g[12]*q0 + g[13]*q1 + g[14]*q2 + g[22];
  double o2 = g[15]*q0 + g[16]*q1 + g[17]*q2 + g[23];
  int cx = (int)((o0 + 51.2)/0.8);
  int cy = (int)((o1 + 51.2)/0.8);
  int cz = (int)((o2 + 10.0)/20.0);
  int rank = cx + cy*128 + cz*16384;
  bool ok = (rank >= 0 && rank < 16384);
  v11_ranks[idx] = ok ? rank : -1;
  if (ok) atomicAdd(&v12_cnt[rank], 1);
}

// exclusive scan over 16384 counts -> offsets (+ cursor copy), single block
__global__ __launch_bounds__(256) void scan_v12(){
  __shared__ int part[256];
  int t = threadIdx.x;
  int base = t*64;
  int s = 0;
  for (int i=0;i<64;i++) s += v12_cnt[base+i];
  part[t] = s;
  __syncthreads();
  if (t == 0){
    int run = 0;
    for (int i=0;i<256;i++){ int v = part[i]; part[i] = run; run += v; }
  }
  __syncthreads();
  int run = part[t];
  for (int i=0;i<64;i++){
    int v = v12_cnt[base+i];
    v12_off[base+i] = run;
    v12_cur[base+i] = run;
    run += v;
  }
}

// scatter point ids into rank-sorted order; store packed (p<<6)|d
__global__ __launch_bounds__(256) void fill_v12(){
  int idx = blockIdx.x*256 + threadIdx.x;
  if (idx >= NPTS) return;
  int rank = v11_ranks[idx];
  if (rank < 0) return;
  int im = idx / 28864;
  int r  = idx % 28864;
  int d  = r / 704; int pix = r % 704;
  int p  = im*704 + pix;
  int pos = atomicAdd(&v12_cur[rank], 1);
  v12_sorted[pos] = (p<<6) | d;
}

// gather: one block per voxel, 4 waves split the point list, lane = channel.
// zero atomics; also zeroes empty voxels (replaces the old bev-zero kernel).
__global__ __launch_bounds__(256) void gather_v12(){
  int rank = blockIdx.x;
  int tid  = threadIdx.x;
  int c = tid & 63, w = tid >> 6;
  int n    = v12_cnt[rank];
  int base = v12_off[rank];
  float acc = 0.f;
  for (int i = w; i < n; i += 4){
    int v = v12_sorted[base + i];
    int p = v >> 6, d = v & 63;
    acc += v11_ctx[(p<<6) | c] * v11_depth[p*41 + d];
  }
  __shared__ float red[256];
  red[tid] = acc;
  __syncthreads();
  if (w == 0){
    float s = red[c] + red[64+c] + red[128+c] + red[192+c];
    v11_bev[(size_t)rank*64 + c] = s;
  }
}

// bev output: [yx][c] -> out1[c][y][x] fp32
__global__ void bevout_v11(float* out1){
  int gid = blockIdx.x*256 + threadIdx.x;
  int c  = gid >> 14;
  int yx = gid & 16383;
  out1[gid] = v11_bev[(size_t)yx*64 + c];
}

// fold enc_w concat([bev,bev]) halves
__global__ void w2_v11(const float* enc_w){
  int gid = blockIdx.x*256 + threadIdx.x;
  if (gid >= 36864) return;
  int o = gid / 576; int rem = gid % 576;
  int ic = rem / 9, t = rem % 9;
  v11_w2[gid] = enc_w[o*1152 + ic*9 + t] + enc_w[o*1152 + (ic+64)*9 + t];
}

// conv2 3x3 SAME + BN2 + ReLU + 7x64 head, fused
__global__ __launch_bounds__(256) void conv2_v11(
    const float* eb, const float* g2, const float* b2_, const float* m2, const float* v2,
    const float* hw, const float* hb, float* out0){
  __shared__ float itile[64*100];     // 25,600 B
  __shared__ float wtile[64*72];      // 18,432 B
  __shared__ float hred[4*64*7];      //  7,168 B
  int tid = threadIdx.x;
  int og  = tid >> 6;
  int pix = tid & 63;
  int py = pix >> 3, px = pix & 7;
  int by = blockIdx.y, bx = blockIdx.x;
  for (int l = tid; l < 6400; l += 256){
    int ic = l / 100, rem = l % 100;
    int iy = rem / 10, ix = rem % 10;
    int gy = by*8 + iy - 1, gx = bx*8 + ix - 1;
    itile[l] = (gy>=0 && gy<128 && gx>=0 && gx<128) ? v11_bev[(size_t)(gy*128+gx)*64 + ic] : 0.f;
  }
  float acc[16];
  #pragma unroll
  for (int j=0;j<16;j++) acc[j]=0.f;
  for (int it=0; it<64; it+=8){
    __syncthreads();
    for (int l = tid; l < 64*72; l += 256){
      int oc = l / 72, rem = l % 72;
      wtile[l] = v11_w2[oc*576 + it*9 + rem];
    }
    __syncthreads();
    for (int icl=0; icl<8; icl++){
      int ic = it + icl;
      const float* ibase = itile + ic*100 + py*10 + px;
      float iv[9];
      #pragma unroll
      for (int t=0;t<9;t++) iv[t] = ibase[(t/3)*10 + (t%3)];
      const float* wbase = wtile + (og*16)*72 + icl*9;
      #pragma unroll
      for (int j=0;j<16;j++){
        #pragma unroll
        for (int t=0;t<9;t++) acc[j] += iv[t]*wbase[j*72+t];
      }
    }
  }
  float part[7];
  #pragma unroll
  for (int o=0;o<7;o++) part[o]=0.f;
  for (int j=0;j<16;j++){
    int oc = og*16+j;
    float scale = g2[oc]/sqrtf(v2[oc]+1e-5f);
    float shift = b2_[oc] - m2[oc]*scale;
    float v = (acc[j] + eb[oc])*scale + shift;
    v = v > 0.f ? v : 0.f;
    #pragma unroll
    for (int o=0;o<7;o++) part[o] += hw[o*64+oc]*v;
  }
  __syncthreads();
  for (int o=0;o<7;o++) hred[(og*64+pix)*7+o] = part[o];
  __syncthreads();
  if (og == 0){
    int gy = by*8+py, gx = bx*8+px;
    for (int o=0;o<7;o++){
      float s = hred[pix*7+o] + hred[(64+pix)*7+o] + hred[(128+pix)*7+o]
              + hred[(192+pix)*7+o] + hb[o];
      out0[o*16384 + gy*128 + gx] = s;
    }
  }
}

extern "C" void kernel_launch(void* const* d_in, const int* in_sizes, int n_in,
                              void* d_out, int out_size, void* d_ws, size_t ws_size,
                              hipStream_t stream){
  const float* imgs       = (const float*)d_in[0];
  const float* rots       = (const float*)d_in[1];
  const float* trans      = (const float*)d_in[2];
  const float* intrins    = (const float*)d_in[3];
  const float* post_rots  = (const float*)d_in[4];
  const float* post_trans = (const float*)d_in[5];
  const float* conv_w     = (const float*)d_in[6];
  const float* conv_b     = (const float*)d_in[7];
  const float* bn1_g      = (const float*)d_in[8];
  const float* bn1_b      = (const float*)d_in[9];
  const float* bn1_m      = (const float*)d_in[10];
  const float* bn1_v      = (const float*)d_in[11];
  const float* depth_w    = (const float*)d_in[12];
  const float* depth_b    = (const float*)d_in[13];
  const float* enc_w      = (const float*)d_in[14];
  const float* enc_b      = (const float*)d_in[15];
  const float* bn2_g      = (const float*)d_in[16];
  const float* bn2_b      = (const float*)d_in[17];
  const float* bn2_m      = (const float*)d_in[18];
  const float* bn2_v      = (const float*)d_in[19];
  const float* head_w     = (const float*)d_in[20];
  const float* head_b     = (const float*)d_in[21];

  float* out0 = (float*)d_out;          // (1,7,128,128)
  float* out1 = out0 + 114688;          // (1,64,128,128)

  zerocnt_v12<<<64, 256, 0, stream>>>();
  geom_v11<<<1, 32, 0, stream>>>(rots, trans, intrins, post_rots, post_trans);
  wt_v11<<<768, 256, 0, stream>>>(conv_w);
  conv1_v11<<<NPATCH/32, 256, 0, stream>>>(imgs, conv_b, bn1_g, bn1_b, bn1_m, bn1_v);
  depth_v11<<<NPATCH/32, 256, 0, stream>>>(depth_w, depth_b);
  rank_v11<<<NPTS/256, 256, 0, stream>>>();
  scan_v12<<<1, 256, 0, stream>>>();
  fill_v12<<<NPTS/256, 256, 0, stream>>>();
  gather_v12<<<16384, 256, 0, stream>>>();
  w2_v11<<<144, 256, 0, stream>>>(enc_w);
  bevout_v11<<<4096, 256, 0, stream>>>(out1);
  conv2_v11<<<dim3(16,16), 256, 0, stream>>>(enc_b, bn2_g, bn2_b, bn2_m, bn2_v,
                                             head_w, head_b, out0);
}

// Round 2
// 554.040 us; speedup vs baseline: 2.0461x; 2.0461x over previous
//
#include <hip/hip_runtime.h>
#include <hip/hip_bf16.h>

#define NPTS 692736      // 24*41*16*44
#define NPATCH 16896     // 24*16*44

// ---------- module-scope device globals ----------
__device__ float  v11_xbuf[NPATCH*256];
__device__ float  v11_ctx[NPATCH*64];
__device__ float  v11_depth[NPATCH*41];
__device__ int    v11_ranks[NPTS];
__device__ float  v11_bev[16384*64];
__device__ float  v11_w2[64*64*9];
__device__ float  v11_wT[768*256];     // conv_w transposed to [k][o]
__device__ double v11_geom[24*24];

// counting-sort state for scatter->gather inversion
__device__ int    v12_cnt[16384];
__device__ int    v12_off[16384];
__device__ int    v12_pos[NPTS];       // position within own voxel
__device__ int2   v12_sorted[NPTS];    // (packed (p<<6)|d, rank) in rank order
__device__ int    v12_total;

__device__ __forceinline__ void inv3_v11(const double* m, double* o){
  double a=m[0],b=m[1],c=m[2],d=m[3],e=m[4],f=m[5],g=m[6],h=m[7],i=m[8];
  double A = e*i - f*h, B = -(d*i - f*g), C = d*h - e*g;
  double det = a*A + b*B + c*C;
  double id = 1.0/det;
  o[0]=A*id;            o[1]=-(b*i - c*h)*id; o[2]=(b*f - c*e)*id;
  o[3]=B*id;            o[4]=(a*i - c*g)*id;  o[5]=-(a*f - c*d)*id;
  o[6]=C*id;            o[7]=-(a*h - b*g)*id; o[8]=(a*e - b*d)*id;
}

// zero bev accumulator + histogram counts
__global__ void zero_v13(){
  int gid = blockIdx.x*256 + threadIdx.x;   // 1,048,576
  v11_bev[gid] = 0.f;
  if (gid < 16384) v12_cnt[gid] = 0;
}

__global__ void geom_v11(const float* rots, const float* trans, const float* intrins,
                         const float* post_rots, const float* post_trans){
  int t = threadIdx.x;
  if (t >= 24) return;
  double pr[9], it[9], r[9];
  for (int i=0;i<9;i++){
    pr[i] = (double)post_rots[t*9+i];
    it[i] = (double)intrins[t*9+i];
    r[i]  = (double)rots[t*9+i];
  }
  double ipr[9], iit[9];
  inv3_v11(pr, ipr); inv3_v11(it, iit);
  double* g = v11_geom + t*24;
  for (int i=0;i<3;i++) for(int j=0;j<3;j++){
    double s=0; for(int k=0;k<3;k++) s += r[i*3+k]*iit[k*3+j];
    g[9+i*3+j]=s;
  }
  for (int i=0;i<9;i++) g[i]   = ipr[i];
  for (int i=0;i<3;i++) g[18+i]= (double)post_trans[t*3+i];
  for (int i=0;i<3;i++) g[21+i]= (double)trans[t*3+i];
}

// transpose conv_w [256 o][768 k] -> wT [768 k][256 o]
__global__ void wt_v11(const float* cw){
  int gid = blockIdx.x*256 + threadIdx.x;   // 196608
  int k = gid >> 8, o = gid & 255;
  v11_wT[gid] = cw[o*768 + k];
}

// conv1 as register-blocked GEMM: block = 32 patches x 256 ch, thread = 8pp x 4ch
__global__ __launch_bounds__(256) void conv1_v11(const float* img,
    const float* cb, const float* g1, const float* b1, const float* m1, const float* v1){
  __shared__ float sp[32*36];    // [kk][pp], stride 36 (16B-aligned, bank-spread)
  __shared__ float sw[32*256];   // [kk][ch]
  int tid = threadIdx.x;
  int cg = tid & 63;             // 64 ch-groups x 4ch
  int pg = tid >> 6;             // 4 patch-groups x 8pp
  int pbase = blockIdx.x*32;
  int im = pbase/704;            // 704 % 32 == 0: all patches same image

  float acc[4][8];
  #pragma unroll
  for (int j=0;j<4;j++)
    #pragma unroll
    for (int i=0;i<8;i++) acc[j][i]=0.f;

  for (int kt=0; kt<768; kt+=32){
    __syncthreads();
    // stage weights (coalesced from transposed wT)
    for (int l = tid; l < 8192; l += 256)
      sw[l] = v11_wT[(kt + (l>>8))*256 + (l&255)];
    // stage patches
    for (int l = tid; l < 1024; l += 256){
      int kk = l>>5, pp = l&31;
      int k = kt + kk;
      int p = pbase + pp;
      int pix = p % 704;
      int ph = pix/44, pw = pix%44;
      int c = k>>8, rem = k&255, ky = rem>>4, kx = rem&15;
      sp[kk*36+pp] = img[(size_t)im*540672 + (size_t)c*180224 +
                         (size_t)(ph*16+ky)*704 + (pw*16+kx)];
    }
    __syncthreads();
    #pragma unroll 8
    for (int kk=0; kk<32; kk++){
      float4 p0 = *(const float4*)&sp[kk*36 + pg*8];
      float4 p1 = *(const float4*)&sp[kk*36 + pg*8 + 4];
      float4 wv = *(const float4*)&sw[kk*256 + cg*4];
      float pv[8] = {p0.x,p0.y,p0.z,p0.w,p1.x,p1.y,p1.z,p1.w};
      float wa[4] = {wv.x,wv.y,wv.z,wv.w};
      #pragma unroll
      for (int j=0;j<4;j++)
        #pragma unroll
        for (int i=0;i<8;i++) acc[j][i] += wa[j]*pv[i];
    }
  }
  // BN + ReLU epilogue, coalesced float4 stores
  float sc[4], sh[4], bi[4];
  #pragma unroll
  for (int j=0;j<4;j++){
    int ch = cg*4+j;
    sc[j] = g1[ch] / sqrtf(v1[ch] + 1e-5f);
    sh[j] = b1[ch] - m1[ch]*sc[j];
    bi[j] = cb[ch];
  }
  #pragma unroll
  for (int i=0;i<8;i++){
    int p = pbase + pg*8 + i;
    float4 v;
    float t0 = (acc[0][i]+bi[0])*sc[0] + sh[0]; v.x = t0>0.f?t0:0.f;
    float t1 = (acc[1][i]+bi[1])*sc[1] + sh[1]; v.y = t1>0.f?t1:0.f;
    float t2 = (acc[2][i]+bi[2])*sc[2] + sh[2]; v.z = t2>0.f?t2:0.f;
    float t3 = (acc[3][i]+bi[3])*sc[3] + sh[3]; v.w = t3>0.f?t3:0.f;
    *(float4*)&v11_xbuf[(size_t)p*256 + cg*4] = v;
  }
}

// depth head as blocked GEMM + softmax + ctx split: block = 32 patches
__global__ __launch_bounds__(256) void depth_v11(const float* dw, const float* db){
  __shared__ float sx[32*260];    // [pp][c], stride 260 (33,280 B)
  __shared__ float sdw[105*36];   // [o][c-chunk 32], stride 36 (15,120 B)
  __shared__ float sy[32*112];    // [pp][o] accum (14,336 B)
  int tid = threadIdx.x;
  int pbase = blockIdx.x*32;
  // load x tile
  for (int l = tid; l < 8192; l += 256){
    int pp = l>>8, c = l&255;
    sx[pp*260+c] = v11_xbuf[(size_t)(pbase+pp)*256 + c];
  }
  // init y with bias
  for (int l = tid; l < 32*105; l += 256){
    int pp = l/105, o = l%105;
    sy[pp*112+o] = db[o];
  }
  int ppg = tid >> 4;   // 16 groups x 2 pp
  int og  = tid & 15;   // 16 groups x 7 o
  for (int ch = 0; ch < 8; ch++){       // 8 chunks of 32 c
    __syncthreads();
    for (int l = tid; l < 105*32; l += 256){
      int o = l>>5, c = l&31;
      sdw[o*36+c] = dw[o*256 + ch*32 + c];
    }
    __syncthreads();
    float a0[7], a1[7];
    #pragma unroll
    for (int oj=0;oj<7;oj++){ a0[oj]=0.f; a1[oj]=0.f; }
    const float* x0 = &sx[(ppg*2  )*260 + ch*32];
    const float* x1 = &sx[(ppg*2+1)*260 + ch*32];
    #pragma unroll
    for (int c4=0; c4<8; c4++){
      float4 xa = *(const float4*)&x0[c4*4];
      float4 xb = *(const float4*)&x1[c4*4];
      #pragma unroll
      for (int oj=0;oj<7;oj++){
        int o = og*7+oj;
        if (o < 105){
          float4 wv = *(const float4*)&sdw[o*36 + c4*4];
          a0[oj] += xa.x*wv.x + xa.y*wv.y + xa.z*wv.z + xa.w*wv.w;
          a1[oj] += xb.x*wv.x + xb.y*wv.y + xb.z*wv.z + xb.w*wv.w;
        }
      }
    }
    #pragma unroll
    for (int oj=0;oj<7;oj++){
      int o = og*7+oj;
      if (o < 105){
        sy[(ppg*2  )*112+o] += a0[oj];
        sy[(ppg*2+1)*112+o] += a1[oj];
      }
    }
  }
  __syncthreads();
  // softmax over first 41 per patch (32 threads)
  if (tid < 32){
    float* y = &sy[tid*112];
    float m = y[0];
    for (int i=1;i<41;i++) m = fmaxf(m, y[i]);
    float s = 0.f;
    for (int i=0;i<41;i++){ float e = expf(y[i]-m); y[i] = e; s += e; }
    float inv = 1.f/s;
    for (int i=0;i<41;i++) y[i] *= inv;
  }
  __syncthreads();
  // write depth + ctx (coalesced)
  for (int l = tid; l < 32*41; l += 256){
    int pp = l/41, dd = l%41;
    v11_depth[(size_t)(pbase+pp)*41 + dd] = sy[pp*112+dd];
  }
  for (int l = tid; l < 32*64; l += 256){
    int pp = l>>6, c = l&63;
    v11_ctx[(size_t)(pbase+pp)*64 + c] = sy[pp*112 + 41 + c];
  }
}

// voxel rank per point + skew-immune LDS histogram + per-point voxel position.
// 1024 points per block (4 per thread), 64KB LDS hist.
__global__ __launch_bounds__(256) void rank_v13(){
  __shared__ int lh[16384];
  int tid = threadIdx.x;
  for (int i = tid; i < 16384; i += 256) lh[i] = 0;
  __syncthreads();
  int base = blockIdx.x*1024;
  int rk[4], lp[4];
  #pragma unroll
  for (int k=0;k<4;k++){
    int idx = base + k*256 + tid;
    rk[k] = -1; lp[k] = 0;
    if (idx < NPTS){
      int im = idx / 28864;
      int r  = idx % 28864;
      int d  = r / 704; int pix = r % 704;
      int h = pix / 44, w = pix % 44;
      const double* g = v11_geom + im*24;
      double fx = (double)w * (703.0/43.0);
      double fy = (double)h * 17.0;
      double fz = 4.0 + (double)d;
      double px = fx - g[18], py = fy - g[19], pz = fz - g[20];
      double q0 = g[0]*px + g[1]*py + g[2]*pz;
      double q1 = g[3]*px + g[4]*py + g[5]*pz;
      double q2 = g[6]*px + g[7]*py + g[8]*pz;
      q0 *= q2; q1 *= q2;
      double o0 = g[9]*q0  + g[10]*q1 + g[11]*q2 + g[21];
      double o1 = g[12]*q0 + g[13]*q1 + g[14]*q2 + g[22];
      double o2 = g[15]*q0 + g[16]*q1 + g[17]*q2 + g[23];
      int cx = (int)((o0 + 51.2)/0.8);
      int cy = (int)((o1 + 51.2)/0.8);
      int cz = (int)((o2 + 10.0)/20.0);
      int rank = cx + cy*128 + cz*16384;
      if (rank >= 0 && rank < 16384){
        rk[k] = rank;
        lp[k] = atomicAdd(&lh[rank], 1);   // position within block's local count
      }
    }
  }
  __syncthreads();
  // flush nonzero bins; lh[bin] becomes this block's global base for that bin
  for (int i = tid; i < 16384; i += 256){
    int h = lh[i];
    if (h) lh[i] = atomicAdd(&v12_cnt[i], h);
  }
  __syncthreads();
  #pragma unroll
  for (int k=0;k<4;k++){
    int idx = base + k*256 + tid;
    if (idx < NPTS){
      v11_ranks[idx] = rk[k];
      if (rk[k] >= 0) v12_pos[idx] = lh[rk[k]] + lp[k];
    }
  }
}

// exclusive scan over 16384 counts -> offsets + total, single block
__global__ __launch_bounds__(256) void scan_v13(){
  __shared__ int part[256];
  int t = threadIdx.x;
  int base = t*64;
  int s = 0;
  for (int i=0;i<64;i++) s += v12_cnt[base+i];
  part[t] = s;
  __syncthreads();
  if (t == 0){
    int run = 0;
    for (int i=0;i<256;i++){ int v = part[i]; part[i] = run; run += v; }
    v12_total = run;
  }
  __syncthreads();
  int run = part[t];
  for (int i=0;i<64;i++){
    v12_off[base+i] = run;
    run += v12_cnt[base+i];
  }
}

// place points into rank-sorted order — NO atomics (position precomputed)
__global__ __launch_bounds__(256) void fill_v13(){
  int idx = blockIdx.x*256 + threadIdx.x;
  if (idx >= NPTS) return;
  int rank = v11_ranks[idx];
  if (rank < 0) return;
  int im = idx / 28864;
  int r  = idx % 28864;
  int d  = r / 704; int pix = r % 704;
  int p  = im*704 + pix;
  int pos = v12_off[rank] + v12_pos[idx];
  v12_sorted[pos] = make_int2((p<<6) | d, rank);
}

// work-balanced segmented reduction: one wave per 64 sorted points, lane = channel.
// Register-accumulate runs of equal rank; atomic flush only at rank transitions.
__global__ __launch_bounds__(256) void gather_v13(){
  int total = v12_total;
  int w = threadIdx.x >> 6;
  int chunk = blockIdx.x*256 + w*64;
  if (chunk >= total) return;
  int lane = threadIdx.x & 63;
  int n = total - chunk; if (n > 64) n = 64;
  // per-lane coalesced load of one point (packed, rank) + its depth weight
  int pv = 0, rv = -1;
  float dv = 0.f;
  if (lane < n){
    int2 sr = v12_sorted[chunk + lane];
    pv = sr.x; rv = sr.y;
    dv = v11_depth[(pv>>6)*41 + (pv & 63)];
  }
  float acc = 0.f;
  int cur = __shfl(rv, 0);
  for (int i = 0; i < n; i++){
    int rk = __shfl(rv, i);
    int pp = __shfl(pv, i) >> 6;
    float dd = __shfl(dv, i);
    if (rk != cur){                       // wave-uniform branch
      atomicAdd(&v11_bev[(size_t)cur*64 + lane], acc);
      acc = 0.f; cur = rk;
    }
    acc += v11_ctx[(pp<<6) | lane] * dd;  // coalesced 256B row read
  }
  atomicAdd(&v11_bev[(size_t)cur*64 + lane], acc);
}

// bev output: [yx][c] -> out1[c][y][x] fp32
__global__ void bevout_v11(float* out1){
  int gid = blockIdx.x*256 + threadIdx.x;
  int c  = gid >> 14;
  int yx = gid & 16383;
  out1[gid] = v11_bev[(size_t)yx*64 + c];
}

// fold enc_w concat([bev,bev]) halves
__global__ void w2_v11(const float* enc_w){
  int gid = blockIdx.x*256 + threadIdx.x;
  if (gid >= 36864) return;
  int o = gid / 576; int rem = gid % 576;
  int ic = rem / 9, t = rem % 9;
  v11_w2[gid] = enc_w[o*1152 + ic*9 + t] + enc_w[o*1152 + (ic+64)*9 + t];
}

// conv2 3x3 SAME + BN2 + ReLU + 7x64 head, fused
__global__ __launch_bounds__(256) void conv2_v11(
    const float* eb, const float* g2, const float* b2_, const float* m2, const float* v2,
    const float* hw, const float* hb, float* out0){
  __shared__ float itile[64*100];     // 25,600 B
  __shared__ float wtile[64*72];      // 18,432 B
  __shared__ float hred[4*64*7];      //  7,168 B
  int tid = threadIdx.x;
  int og  = tid >> 6;
  int pix = tid & 63;
  int py = pix >> 3, px = pix & 7;
  int by = blockIdx.y, bx = blockIdx.x;
  for (int l = tid; l < 6400; l += 256){
    int ic = l / 100, rem = l % 100;
    int iy = rem / 10, ix = rem % 10;
    int gy = by*8 + iy - 1, gx = bx*8 + ix - 1;
    itile[l] = (gy>=0 && gy<128 && gx>=0 && gx<128) ? v11_bev[(size_t)(gy*128+gx)*64 + ic] : 0.f;
  }
  float acc[16];
  #pragma unroll
  for (int j=0;j<16;j++) acc[j]=0.f;
  for (int it=0; it<64; it+=8){
    __syncthreads();
    for (int l = tid; l < 64*72; l += 256){
      int oc = l / 72, rem = l % 72;
      wtile[l] = v11_w2[oc*576 + it*9 + rem];
    }
    __syncthreads();
    for (int icl=0; icl<8; icl++){
      int ic = it + icl;
      const float* ibase = itile + ic*100 + py*10 + px;
      float iv[9];
      #pragma unroll
      for (int t=0;t<9;t++) iv[t] = ibase[(t/3)*10 + (t%3)];
      const float* wbase = wtile + (og*16)*72 + icl*9;
      #pragma unroll
      for (int j=0;j<16;j++){
        #pragma unroll
        for (int t=0;t<9;t++) acc[j] += iv[t]*wbase[j*72+t];
      }
    }
  }
  float part[7];
  #pragma unroll
  for (int o=0;o<7;o++) part[o]=0.f;
  for (int j=0;j<16;j++){
    int oc = og*16+j;
    float scale = g2[oc]/sqrtf(v2[oc]+1e-5f);
    float shift = b2_[oc] - m2[oc]*scale;
    float v = (acc[j] + eb[oc])*scale + shift;
    v = v > 0.f ? v : 0.f;
    #pragma unroll
    for (int o=0;o<7;o++) part[o] += hw[o*64+oc]*v;
  }
  __syncthreads();
  for (int o=0;o<7;o++) hred[(og*64+pix)*7+o] = part[o];
  __syncthreads();
  if (og == 0){
    int gy = by*8+py, gx = bx*8+px;
    for (int o=0;o<7;o++){
      float s = hred[pix*7+o] + hred[(64+pix)*7+o] + hred[(128+pix)*7+o]
              + hred[(192+pix)*7+o] + hb[o];
      out0[o*16384 + gy*128 + gx] = s;
    }
  }
}

extern "C" void kernel_launch(void* const* d_in, const int* in_sizes, int n_in,
                              void* d_out, int out_size, void* d_ws, size_t ws_size,
                              hipStream_t stream){
  const float* imgs       = (const float*)d_in[0];
  const float* rots       = (const float*)d_in[1];
  const float* trans      = (const float*)d_in[2];
  const float* intrins    = (const float*)d_in[3];
  const float* post_rots  = (const float*)d_in[4];
  const float* post_trans = (const float*)d_in[5];
  const float* conv_w     = (const float*)d_in[6];
  const float* conv_b     = (const float*)d_in[7];
  const float* bn1_g      = (const float*)d_in[8];
  const float* bn1_b      = (const float*)d_in[9];
  const float* bn1_m      = (const float*)d_in[10];
  const float* bn1_v      = (const float*)d_in[11];
  const float* depth_w    = (const float*)d_in[12];
  const float* depth_b    = (const float*)d_in[13];
  const float* enc_w      = (const float*)d_in[14];
  const float* enc_b      = (const float*)d_in[15];
  const float* bn2_g      = (const float*)d_in[16];
  const float* bn2_b      = (const float*)d_in[17];
  const float* bn2_m      = (const float*)d_in[18];
  const float* bn2_v      = (const float*)d_in[19];
  const float* head_w     = (const float*)d_in[20];
  const float* head_b     = (const float*)d_in[21];

  float* out0 = (float*)d_out;          // (1,7,128,128)
  float* out1 = out0 + 114688;          // (1,64,128,128)

  zero_v13<<<4096, 256, 0, stream>>>();
  geom_v11<<<1, 32, 0, stream>>>(rots, trans, intrins, post_rots, post_trans);
  wt_v11<<<768, 256, 0, stream>>>(conv_w);
  conv1_v11<<<NPATCH/32, 256, 0, stream>>>(imgs, conv_b, bn1_g, bn1_b, bn1_m, bn1_v);
  depth_v11<<<NPATCH/32, 256, 0, stream>>>(depth_w, depth_b);
  rank_v13<<<(NPTS+1023)/1024, 256, 0, stream>>>();
  scan_v13<<<1, 256, 0, stream>>>();
  fill_v13<<<NPTS/256, 256, 0, stream>>>();
  gather_v13<<<NPTS/256, 256, 0, stream>>>();
  w2_v11<<<144, 256, 0, stream>>>(enc_w);
  bevout_v11<<<4096, 256, 0, stream>>>(out1);
  conv2_v11<<<dim3(16,16), 256, 0, stream>>>(enc_b, bn2_g, bn2_b, bn2_m, bn2_v,
                                             head_w, head_b, out0);
}

// Round 3
// 440.329 us; speedup vs baseline: 2.5745x; 1.2582x over previous
//
#include <hip/hip_runtime.h>
#include <hip/hip_bf16.h>
#include <hip/hip_fp16.h>

#define NPTS 692736      // 24*41*16*44
#define NPATCH 16896     // 24*16*44

typedef _Float16 h16;
typedef __attribute__((ext_vector_type(4))) _Float16 half4v;
typedef __attribute__((ext_vector_type(8))) _Float16 half8v;
typedef __attribute__((ext_vector_type(4))) float f32x4;

// ---------- module-scope device globals ----------
__device__ float  v11_xbuf[NPATCH*256];
__device__ float  v11_ctx[NPATCH*64];
__device__ float  v11_depth[NPATCH*41];
__device__ int    v11_ranks[NPTS];
__device__ float  v11_bev[16384*64];
__device__ float  v11_w2[64*64*9];
__device__ double v11_geom[24*24];

// f16 hi/lo split conv1 weights, [o][k] flat (o*768+k)
__device__ h16    v14_whi[256*768];
__device__ h16    v14_wlo[256*768];

// counting-sort state for scatter->gather inversion
__device__ int    v12_cnt[16384];
__device__ int    v12_off[16384];
__device__ int    v12_pos[NPTS];       // position within own voxel
__device__ int2   v12_sorted[NPTS];    // (packed (p<<6)|d, rank) in rank order
__device__ int    v12_total;

__device__ __forceinline__ void inv3_v11(const double* m, double* o){
  double a=m[0],b=m[1],c=m[2],d=m[3],e=m[4],f=m[5],g=m[6],h=m[7],i=m[8];
  double A = e*i - f*h, B = -(d*i - f*g), C = d*h - e*g;
  double det = a*A + b*B + c*C;
  double id = 1.0/det;
  o[0]=A*id;            o[1]=-(b*i - c*h)*id; o[2]=(b*f - c*e)*id;
  o[3]=B*id;            o[4]=(a*i - c*g)*id;  o[5]=-(a*f - c*d)*id;
  o[6]=C*id;            o[7]=-(a*h - b*g)*id; o[8]=(a*e - b*d)*id;
}

// zero bev accumulator + histogram counts
__global__ void zero_v13(){
  int gid = blockIdx.x*256 + threadIdx.x;   // 1,048,576
  v11_bev[gid] = 0.f;
  if (gid < 16384) v12_cnt[gid] = 0;
}

__global__ void geom_v11(const float* rots, const float* trans, const float* intrins,
                         const float* post_rots, const float* post_trans){
  int t = threadIdx.x;
  if (t >= 24) return;
  double pr[9], it[9], r[9];
  for (int i=0;i<9;i++){
    pr[i] = (double)post_rots[t*9+i];
    it[i] = (double)intrins[t*9+i];
    r[i]  = (double)rots[t*9+i];
  }
  double ipr[9], iit[9];
  inv3_v11(pr, ipr); inv3_v11(it, iit);
  double* g = v11_geom + t*24;
  for (int i=0;i<3;i++) for(int j=0;j<3;j++){
    double s=0; for(int k=0;k<3;k++) s += r[i*3+k]*iit[k*3+j];
    g[9+i*3+j]=s;
  }
  for (int i=0;i<9;i++) g[i]   = ipr[i];
  for (int i=0;i<3;i++) g[18+i]= (double)post_trans[t*3+i];
  for (int i=0;i<3;i++) g[21+i]= (double)trans[t*3+i];
}

// split conv_w into f16 hi/lo, layout [o][k] (same flat order as conv_w)
__global__ void wt_v14(const float* cw){
  int gid = blockIdx.x*256 + threadIdx.x;   // 196608
  float x = cw[gid];
  h16 hi = (h16)x;
  h16 lo = (h16)(x - (float)hi);
  v14_whi[gid] = hi;
  v14_wlo[gid] = lo;
}

// conv1 as f16-split MFMA GEMM: C[16896x256] = A[16896x768] * W[768x256]
// block tile 64(M) x 128(N) x 32(K), 4 waves, wave sub-tile 32x64.
// A,B LDS layout: [row][k] with row stride 40 halves (80B: bank-spread, 16B-aligned)
__global__ __launch_bounds__(256) void conv1_v14(const float* img,
    const float* cb, const float* g1, const float* b1, const float* m1, const float* v1){
  __shared__ h16 Ah[64*40];
  __shared__ h16 Al[64*40];
  __shared__ h16 Bh[128*40];
  __shared__ h16 Bl[128*40];
  int tid  = threadIdx.x;
  int lane = tid & 63, wv = tid >> 6;
  int wr = wv >> 1, wc = wv & 1;          // wave grid 2(M) x 2(N)
  int pbase = blockIdx.x * 64;
  int obase = blockIdx.y * 128;

  // --- A staging descriptors (2 float4-quads/thread/K-step), hoisted ---
  const float* abase[2];
  int app[2], akq[2];
  #pragma unroll
  for (int i=0;i<2;i++){
    int l = tid + i*256;          // 0..511
    int pp = l>>3; int kq4 = (l&7)*4;
    app[i] = pp; akq[i] = kq4;
    int p = pbase + pp;
    int im = p/704; int pix = p%704;
    int ph = pix/44, pw = pix%44;
    abase[i] = img + (size_t)im*540672 + (size_t)ph*16*704 + pw*16;
  }
  // --- W staging descriptors (4 half4-quads/thread/K-step per array) ---
  const h16* wsh[4]; const h16* wsl[4];
  int wo[4], wkq[4];
  #pragma unroll
  for (int i=0;i<4;i++){
    int l = tid + i*256;          // 0..1023
    int o = l>>3; int kq4 = (l&7)*4;
    wo[i] = o; wkq[i] = kq4;
    wsh[i] = v14_whi + (size_t)(obase+o)*768 + kq4;
    wsl[i] = v14_wlo + (size_t)(obase+o)*768 + kq4;
  }

  f32x4 acc[2][4];
  #pragma unroll
  for (int mf=0;mf<2;mf++)
    #pragma unroll
    for (int nf=0;nf<4;nf++) acc[mf][nf] = (f32x4){0.f,0.f,0.f,0.f};

  int fr = lane & 15, fg = lane >> 4;
  int koff = fg*8;

  for (int kt=0; kt<768; kt+=32){
    __syncthreads();
    // stage A (im2col + f16 split)
    #pragma unroll
    for (int i=0;i<2;i++){
      int k0 = kt + akq[i];
      int c = k0>>8, rem = k0&255, ky = rem>>4, kx = rem&15;
      float4 v = *(const float4*)(abase[i] + (size_t)c*180224 + ky*704 + kx);
      half4v hv, lv;
      hv.x = (h16)v.x; lv.x = (h16)(v.x - (float)hv.x);
      hv.y = (h16)v.y; lv.y = (h16)(v.y - (float)hv.y);
      hv.z = (h16)v.z; lv.z = (h16)(v.z - (float)hv.z);
      hv.w = (h16)v.w; lv.w = (h16)(v.w - (float)hv.w);
      *(half4v*)&Ah[app[i]*40 + akq[i]] = hv;
      *(half4v*)&Al[app[i]*40 + akq[i]] = lv;
    }
    // stage W (pre-split in global)
    #pragma unroll
    for (int i=0;i<4;i++){
      half4v hv = *(const half4v*)(wsh[i] + kt);
      half4v lv = *(const half4v*)(wsl[i] + kt);
      *(half4v*)&Bh[wo[i]*40 + wkq[i]] = hv;
      *(half4v*)&Bl[wo[i]*40 + wkq[i]] = lv;
    }
    __syncthreads();
    // fragments
    half8v ah[2], al[2], bh[4], bl[4];
    #pragma unroll
    for (int mf=0;mf<2;mf++){
      int row = wr*32 + mf*16 + fr;
      ah[mf] = *(const half8v*)&Ah[row*40 + koff];
      al[mf] = *(const half8v*)&Al[row*40 + koff];
    }
    #pragma unroll
    for (int nf=0;nf<4;nf++){
      int col = wc*64 + nf*16 + fr;
      bh[nf] = *(const half8v*)&Bh[col*40 + koff];
      bl[nf] = *(const half8v*)&Bl[col*40 + koff];
    }
    #pragma unroll
    for (int mf=0;mf<2;mf++)
      #pragma unroll
      for (int nf=0;nf<4;nf++){
        acc[mf][nf] = __builtin_amdgcn_mfma_f32_16x16x32_f16(ah[mf], bh[nf], acc[mf][nf], 0,0,0);
        acc[mf][nf] = __builtin_amdgcn_mfma_f32_16x16x32_f16(ah[mf], bl[nf], acc[mf][nf], 0,0,0);
        acc[mf][nf] = __builtin_amdgcn_mfma_f32_16x16x32_f16(al[mf], bh[nf], acc[mf][nf], 0,0,0);
      }
  }
  // epilogue: BN + ReLU, C layout col=lane&15, row=(lane>>4)*4+j
  #pragma unroll
  for (int nf=0;nf<4;nf++){
    int ch = obase + wc*64 + nf*16 + fr;
    float sc = g1[ch] / sqrtf(v1[ch] + 1e-5f);
    float sh = b1[ch] - m1[ch]*sc;
    float bi = cb[ch];
    #pragma unroll
    for (int mf=0;mf<2;mf++){
      #pragma unroll
      for (int j=0;j<4;j++){
        int p = pbase + wr*32 + mf*16 + fg*4 + j;
        float t = (acc[mf][nf][j] + bi)*sc + sh;
        v11_xbuf[(size_t)p*256 + ch] = t > 0.f ? t : 0.f;
      }
    }
  }
}

// depth head as blocked GEMM + softmax + ctx split: block = 32 patches
__global__ __launch_bounds__(256) void depth_v11(const float* dw, const float* db){
  __shared__ float sx[32*260];    // [pp][c], stride 260 (33,280 B)
  __shared__ float sdw[105*36];   // [o][c-chunk 32], stride 36 (15,120 B)
  __shared__ float sy[32*112];    // [pp][o] accum (14,336 B)
  int tid = threadIdx.x;
  int pbase = blockIdx.x*32;
  // load x tile
  for (int l = tid; l < 8192; l += 256){
    int pp = l>>8, c = l&255;
    sx[pp*260+c] = v11_xbuf[(size_t)(pbase+pp)*256 + c];
  }
  // init y with bias
  for (int l = tid; l < 32*105; l += 256){
    int pp = l/105, o = l%105;
    sy[pp*112+o] = db[o];
  }
  int ppg = tid >> 4;   // 16 groups x 2 pp
  int og  = tid & 15;   // 16 groups x 7 o
  for (int ch = 0; ch < 8; ch++){       // 8 chunks of 32 c
    __syncthreads();
    for (int l = tid; l < 105*32; l += 256){
      int o = l>>5, c = l&31;
      sdw[o*36+c] = dw[o*256 + ch*32 + c];
    }
    __syncthreads();
    float a0[7], a1[7];
    #pragma unroll
    for (int oj=0;oj<7;oj++){ a0[oj]=0.f; a1[oj]=0.f; }
    const float* x0 = &sx[(ppg*2  )*260 + ch*32];
    const float* x1 = &sx[(ppg*2+1)*260 + ch*32];
    #pragma unroll
    for (int c4=0; c4<8; c4++){
      float4 xa = *(const float4*)&x0[c4*4];
      float4 xb = *(const float4*)&x1[c4*4];
      #pragma unroll
      for (int oj=0;oj<7;oj++){
        int o = og*7+oj;
        if (o < 105){
          float4 wv = *(const float4*)&sdw[o*36 + c4*4];
          a0[oj] += xa.x*wv.x + xa.y*wv.y + xa.z*wv.z + xa.w*wv.w;
          a1[oj] += xb.x*wv.x + xb.y*wv.y + xb.z*wv.z + xb.w*wv.w;
        }
      }
    }
    #pragma unroll
    for (int oj=0;oj<7;oj++){
      int o = og*7+oj;
      if (o < 105){
        sy[(ppg*2  )*112+o] += a0[oj];
        sy[(ppg*2+1)*112+o] += a1[oj];
      }
    }
  }
  __syncthreads();
  // softmax over first 41 per patch (32 threads)
  if (tid < 32){
    float* y = &sy[tid*112];
    float m = y[0];
    for (int i=1;i<41;i++) m = fmaxf(m, y[i]);
    float s = 0.f;
    for (int i=0;i<41;i++){ float e = expf(y[i]-m); y[i] = e; s += e; }
    float inv = 1.f/s;
    for (int i=0;i<41;i++) y[i] *= inv;
  }
  __syncthreads();
  // write depth + ctx (coalesced)
  for (int l = tid; l < 32*41; l += 256){
    int pp = l/41, dd = l%41;
    v11_depth[(size_t)(pbase+pp)*41 + dd] = sy[pp*112+dd];
  }
  for (int l = tid; l < 32*64; l += 256){
    int pp = l>>6, c = l&63;
    v11_ctx[(size_t)(pbase+pp)*64 + c] = sy[pp*112 + 41 + c];
  }
}

// voxel rank per point + skew-immune LDS histogram + per-point voxel position.
// 1024 points per block (4 per thread), 64KB LDS hist.
__global__ __launch_bounds__(256) void rank_v13(){
  __shared__ int lh[16384];
  int tid = threadIdx.x;
  for (int i = tid; i < 16384; i += 256) lh[i] = 0;
  __syncthreads();
  int base = blockIdx.x*1024;
  int rk[4], lp[4];
  #pragma unroll
  for (int k=0;k<4;k++){
    int idx = base + k*256 + tid;
    rk[k] = -1; lp[k] = 0;
    if (idx < NPTS){
      int im = idx / 28864;
      int r  = idx % 28864;
      int d  = r / 704; int pix = r % 704;
      int h = pix / 44, w = pix % 44;
      const double* g = v11_geom + im*24;
      double fx = (double)w * (703.0/43.0);
      double fy = (double)h * 17.0;
      double fz = 4.0 + (double)d;
      double px = fx - g[18], py = fy - g[19], pz = fz - g[20];
      double q0 = g[0]*px + g[1]*py + g[2]*pz;
      double q1 = g[3]*px + g[4]*py + g[5]*pz;
      double q2 = g[6]*px + g[7]*py + g[8]*pz;
      q0 *= q2; q1 *= q2;
      double o0 = g[9]*q0  + g[10]*q1 + g[11]*q2 + g[21];
      double o1 = g[12]*q0 + g[13]*q1 + g[14]*q2 + g[22];
      double o2 = g[15]*q0 + g[16]*q1 + g[17]*q2 + g[23];
      int cx = (int)((o0 + 51.2)/0.8);
      int cy = (int)((o1 + 51.2)/0.8);
      int cz = (int)((o2 + 10.0)/20.0);
      int rank = cx + cy*128 + cz*16384;
      if (rank >= 0 && rank < 16384){
        rk[k] = rank;
        lp[k] = atomicAdd(&lh[rank], 1);   // position within block's local count
      }
    }
  }
  __syncthreads();
  // flush nonzero bins; lh[bin] becomes this block's global base for that bin
  for (int i = tid; i < 16384; i += 256){
    int h = lh[i];
    if (h) lh[i] = atomicAdd(&v12_cnt[i], h);
  }
  __syncthreads();
  #pragma unroll
  for (int k=0;k<4;k++){
    int idx = base + k*256 + tid;
    if (idx < NPTS){
      v11_ranks[idx] = rk[k];
      if (rk[k] >= 0) v12_pos[idx] = lh[rk[k]] + lp[k];
    }
  }
}

// exclusive scan over 16384 counts -> offsets + total, single block
__global__ __launch_bounds__(256) void scan_v13(){
  __shared__ int part[256];
  int t = threadIdx.x;
  int base = t*64;
  int s = 0;
  for (int i=0;i<64;i++) s += v12_cnt[base+i];
  part[t] = s;
  __syncthreads();
  if (t == 0){
    int run = 0;
    for (int i=0;i<256;i++){ int v = part[i]; part[i] = run; run += v; }
    v12_total = run;
  }
  __syncthreads();
  int run = part[t];
  for (int i=0;i<64;i++){
    v12_off[base+i] = run;
    run += v12_cnt[base+i];
  }
}

// place points into rank-sorted order — NO atomics (position precomputed)
__global__ __launch_bounds__(256) void fill_v13(){
  int idx = blockIdx.x*256 + threadIdx.x;
  if (idx >= NPTS) return;
  int rank = v11_ranks[idx];
  if (rank < 0) return;
  int im = idx / 28864;
  int r  = idx % 28864;
  int d  = r / 704; int pix = r % 704;
  int p  = im*704 + pix;
  int pos = v12_off[rank] + v12_pos[idx];
  v12_sorted[pos] = make_int2((p<<6) | d, rank);
}

// work-balanced segmented reduction: one wave per 64 sorted points, lane = channel.
// Register-accumulate runs of equal rank; atomic flush only at rank transitions.
__global__ __launch_bounds__(256) void gather_v13(){
  int total = v12_total;
  int w = threadIdx.x >> 6;
  int chunk = blockIdx.x*256 + w*64;
  if (chunk >= total) return;
  int lane = threadIdx.x & 63;
  int n = total - chunk; if (n > 64) n = 64;
  // per-lane coalesced load of one point (packed, rank) + its depth weight
  int pv = 0, rv = -1;
  float dv = 0.f;
  if (lane < n){
    int2 sr = v12_sorted[chunk + lane];
    pv = sr.x; rv = sr.y;
    dv = v11_depth[(pv>>6)*41 + (pv & 63)];
  }
  float acc = 0.f;
  int cur = __shfl(rv, 0);
  for (int i = 0; i < n; i++){
    int rk = __shfl(rv, i);
    int pp = __shfl(pv, i) >> 6;
    float dd = __shfl(dv, i);
    if (rk != cur){                       // wave-uniform branch
      atomicAdd(&v11_bev[(size_t)cur*64 + lane], acc);
      acc = 0.f; cur = rk;
    }
    acc += v11_ctx[(pp<<6) | lane] * dd;  // coalesced 256B row read
  }
  atomicAdd(&v11_bev[(size_t)cur*64 + lane], acc);
}

// bev output: [yx][c] -> out1[c][y][x] fp32
__global__ void bevout_v11(float* out1){
  int gid = blockIdx.x*256 + threadIdx.x;
  int c  = gid >> 14;
  int yx = gid & 16383;
  out1[gid] = v11_bev[(size_t)yx*64 + c];
}

// fold enc_w concat([bev,bev]) halves
__global__ void w2_v11(const float* enc_w){
  int gid = blockIdx.x*256 + threadIdx.x;
  if (gid >= 36864) return;
  int o = gid / 576; int rem = gid % 576;
  int ic = rem / 9, t = rem % 9;
  v11_w2[gid] = enc_w[o*1152 + ic*9 + t] + enc_w[o*1152 + (ic+64)*9 + t];
}

// conv2 3x3 SAME + BN2 + ReLU + 7x64 head, fused
__global__ __launch_bounds__(256) void conv2_v11(
    const float* eb, const float* g2, const float* b2_, const float* m2, const float* v2,
    const float* hw, const float* hb, float* out0){
  __shared__ float itile[64*100];     // 25,600 B
  __shared__ float wtile[64*72];      // 18,432 B
  __shared__ float hred[4*64*7];      //  7,168 B
  int tid = threadIdx.x;
  int og  = tid >> 6;
  int pix = tid & 63;
  int py = pix >> 3, px = pix & 7;
  int by = blockIdx.y, bx = blockIdx.x;
  for (int l = tid; l < 6400; l += 256){
    int ic = l / 100, rem = l % 100;
    int iy = rem / 10, ix = rem % 10;
    int gy = by*8 + iy - 1, gx = bx*8 + ix - 1;
    itile[l] = (gy>=0 && gy<128 && gx>=0 && gx<128) ? v11_bev[(size_t)(gy*128+gx)*64 + ic] : 0.f;
  }
  float acc[16];
  #pragma unroll
  for (int j=0;j<16;j++) acc[j]=0.f;
  for (int it=0; it<64; it+=8){
    __syncthreads();
    for (int l = tid; l < 64*72; l += 256){
      int oc = l / 72, rem = l % 72;
      wtile[l] = v11_w2[oc*576 + it*9 + rem];
    }
    __syncthreads();
    for (int icl=0; icl<8; icl++){
      int ic = it + icl;
      const float* ibase = itile + ic*100 + py*10 + px;
      float iv[9];
      #pragma unroll
      for (int t=0;t<9;t++) iv[t] = ibase[(t/3)*10 + (t%3)];
      const float* wbase = wtile + (og*16)*72 + icl*9;
      #pragma unroll
      for (int j=0;j<16;j++){
        #pragma unroll
        for (int t=0;t<9;t++) acc[j] += iv[t]*wbase[j*72+t];
      }
    }
  }
  float part[7];
  #pragma unroll
  for (int o=0;o<7;o++) part[o]=0.f;
  for (int j=0;j<16;j++){
    int oc = og*16+j;
    float scale = g2[oc]/sqrtf(v2[oc]+1e-5f);
    float shift = b2_[oc] - m2[oc]*scale;
    float v = (acc[j] + eb[oc])*scale + shift;
    v = v > 0.f ? v : 0.f;
    #pragma unroll
    for (int o=0;o<7;o++) part[o] += hw[o*64+oc]*v;
  }
  __syncthreads();
  for (int o=0;o<7;o++) hred[(og*64+pix)*7+o] = part[o];
  __syncthreads();
  if (og == 0){
    int gy = by*8+py, gx = bx*8+px;
    for (int o=0;o<7;o++){
      float s = hred[pix*7+o] + hred[(64+pix)*7+o] + hred[(128+pix)*7+o]
              + hred[(192+pix)*7+o] + hb[o];
      out0[o*16384 + gy*128 + gx] = s;
    }
  }
}

extern "C" void kernel_launch(void* const* d_in, const int* in_sizes, int n_in,
                              void* d_out, int out_size, void* d_ws, size_t ws_size,
                              hipStream_t stream){
  const float* imgs       = (const float*)d_in[0];
  const float* rots       = (const float*)d_in[1];
  const float* trans      = (const float*)d_in[2];
  const float* intrins    = (const float*)d_in[3];
  const float* post_rots  = (const float*)d_in[4];
  const float* post_trans = (const float*)d_in[5];
  const float* conv_w     = (const float*)d_in[6];
  const float* conv_b     = (const float*)d_in[7];
  const float* bn1_g      = (const float*)d_in[8];
  const float* bn1_b      = (const float*)d_in[9];
  const float* bn1_m      = (const float*)d_in[10];
  const float* bn1_v      = (const float*)d_in[11];
  const float* depth_w    = (const float*)d_in[12];
  const float* depth_b    = (const float*)d_in[13];
  const float* enc_w      = (const float*)d_in[14];
  const float* enc_b      = (const float*)d_in[15];
  const float* bn2_g      = (const float*)d_in[16];
  const float* bn2_b      = (const float*)d_in[17];
  const float* bn2_m      = (const float*)d_in[18];
  const float* bn2_v      = (const float*)d_in[19];
  const float* head_w     = (const float*)d_in[20];
  const float* head_b     = (const float*)d_in[21];

  float* out0 = (float*)d_out;          // (1,7,128,128)
  float* out1 = out0 + 114688;          // (1,64,128,128)

  zero_v13<<<4096, 256, 0, stream>>>();
  geom_v11<<<1, 32, 0, stream>>>(rots, trans, intrins, post_rots, post_trans);
  wt_v14<<<768, 256, 0, stream>>>(conv_w);
  conv1_v14<<<dim3(264, 2), 256, 0, stream>>>(imgs, conv_b, bn1_g, bn1_b, bn1_m, bn1_v);
  depth_v11<<<NPATCH/32, 256, 0, stream>>>(depth_w, depth_b);
  rank_v13<<<(NPTS+1023)/1024, 256, 0, stream>>>();
  scan_v13<<<1, 256, 0, stream>>>();
  fill_v13<<<NPTS/256, 256, 0, stream>>>();
  gather_v13<<<NPTS/256, 256, 0, stream>>>();
  w2_v11<<<144, 256, 0, stream>>>(enc_w);
  bevout_v11<<<4096, 256, 0, stream>>>(out1);
  conv2_v11<<<dim3(16,16), 256, 0, stream>>>(enc_b, bn2_g, bn2_b, bn2_m, bn2_v,
                                             head_w, head_b, out0);
}

// Round 4
// 348.945 us; speedup vs baseline: 3.2487x; 1.2619x over previous
//
#include <hip/hip_runtime.h>
#include <hip/hip_bf16.h>
#include <hip/hip_fp16.h>

#define NPTS 692736      // 24*41*16*44
#define NPATCH 16896     // 24*16*44

typedef _Float16 h16;
typedef __attribute__((ext_vector_type(4))) _Float16 half4v;
typedef __attribute__((ext_vector_type(8))) _Float16 half8v;
typedef __attribute__((ext_vector_type(4))) float f32x4;

// ---------- module-scope device globals ----------
__device__ float  v11_xbuf[NPATCH*256];
__device__ float  v11_ctx[NPATCH*64];
__device__ float  v11_depth[NPATCH*41];
__device__ int    v11_ranks[NPTS];
__device__ float  v11_bev[16384*64];
__device__ float  v11_w2[64*64*9];
__device__ double v11_geom[24*24];

// f16 hi/lo split conv1 weights, [o][k] flat (o*768+k)
__device__ h16    v14_whi[256*768];
__device__ h16    v14_wlo[256*768];

// f16 hi/lo split depth weights, padded [112][256] ([o][c])
__device__ h16    v15_dwhi[112*256];
__device__ h16    v15_dwlo[112*256];

// counting-sort state for scatter->gather inversion
__device__ int    v12_cnt[16384];
__device__ int    v12_off[16384];
__device__ int    v12_pos[NPTS];       // position within own voxel
__device__ int2   v12_sorted[NPTS];    // (packed (p<<6)|d, rank) in rank order
__device__ int    v12_total;

__device__ __forceinline__ void inv3_v11(const double* m, double* o){
  double a=m[0],b=m[1],c=m[2],d=m[3],e=m[4],f=m[5],g=m[6],h=m[7],i=m[8];
  double A = e*i - f*h, B = -(d*i - f*g), C = d*h - e*g;
  double det = a*A + b*B + c*C;
  double id = 1.0/det;
  o[0]=A*id;            o[1]=-(b*i - c*h)*id; o[2]=(b*f - c*e)*id;
  o[3]=B*id;            o[4]=(a*i - c*g)*id;  o[5]=-(a*f - c*d)*id;
  o[6]=C*id;            o[7]=-(a*h - b*g)*id; o[8]=(a*e - b*d)*id;
}

// zero bev accumulator + histogram counts
__global__ void zero_v13(){
  int gid = blockIdx.x*256 + threadIdx.x;   // 1,048,576
  v11_bev[gid] = 0.f;
  if (gid < 16384) v12_cnt[gid] = 0;
}

__global__ void geom_v11(const float* rots, const float* trans, const float* intrins,
                         const float* post_rots, const float* post_trans){
  int t = threadIdx.x;
  if (t >= 24) return;
  double pr[9], it[9], r[9];
  for (int i=0;i<9;i++){
    pr[i] = (double)post_rots[t*9+i];
    it[i] = (double)intrins[t*9+i];
    r[i]  = (double)rots[t*9+i];
  }
  double ipr[9], iit[9];
  inv3_v11(pr, ipr); inv3_v11(it, iit);
  double* g = v11_geom + t*24;
  for (int i=0;i<3;i++) for(int j=0;j<3;j++){
    double s=0; for(int k=0;k<3;k++) s += r[i*3+k]*iit[k*3+j];
    g[9+i*3+j]=s;
  }
  for (int i=0;i<9;i++) g[i]   = ipr[i];
  for (int i=0;i<3;i++) g[18+i]= (double)post_trans[t*3+i];
  for (int i=0;i<3;i++) g[21+i]= (double)trans[t*3+i];
}

// split conv_w into f16 hi/lo, layout [o][k] (same flat order as conv_w)
__global__ void wt_v14(const float* cw){
  int gid = blockIdx.x*256 + threadIdx.x;   // 196608
  float x = cw[gid];
  h16 hi = (h16)x;
  h16 lo = (h16)(x - (float)hi);
  v14_whi[gid] = hi;
  v14_wlo[gid] = lo;
}

// split depth_w [105][256] into f16 hi/lo padded to [112][256]
__global__ void wtd_v15(const float* dw){
  int gid = blockIdx.x*256 + threadIdx.x;   // 28672
  int o = gid >> 8, c = gid & 255;
  float x = (o < 105) ? dw[o*256 + c] : 0.f;
  h16 hi = (h16)x;
  h16 lo = (h16)(x - (float)hi);
  v15_dwhi[gid] = hi;
  v15_dwlo[gid] = lo;
}

// conv1 as f16-split MFMA GEMM: C[16896x256] = A[16896x768] * W[768x256]
// block tile 64(M) x 128(N) x 32(K), 4 waves, wave sub-tile 32x64.
// A,B LDS layout: [row][k] with row stride 40 halves (80B: bank-spread, 16B-aligned)
__global__ __launch_bounds__(256) void conv1_v14(const float* img,
    const float* cb, const float* g1, const float* b1, const float* m1, const float* v1){
  __shared__ h16 Ah[64*40];
  __shared__ h16 Al[64*40];
  __shared__ h16 Bh[128*40];
  __shared__ h16 Bl[128*40];
  int tid  = threadIdx.x;
  int lane = tid & 63, wv = tid >> 6;
  int wr = wv >> 1, wc = wv & 1;          // wave grid 2(M) x 2(N)
  int pbase = blockIdx.x * 64;
  int obase = blockIdx.y * 128;

  // --- A staging descriptors (2 float4-quads/thread/K-step), hoisted ---
  const float* abase[2];
  int app[2], akq[2];
  #pragma unroll
  for (int i=0;i<2;i++){
    int l = tid + i*256;          // 0..511
    int pp = l>>3; int kq4 = (l&7)*4;
    app[i] = pp; akq[i] = kq4;
    int p = pbase + pp;
    int im = p/704; int pix = p%704;
    int ph = pix/44, pw = pix%44;
    abase[i] = img + (size_t)im*540672 + (size_t)ph*16*704 + pw*16;
  }
  // --- W staging descriptors (4 half4-quads/thread/K-step per array) ---
  const h16* wsh[4]; const h16* wsl[4];
  int wo[4], wkq[4];
  #pragma unroll
  for (int i=0;i<4;i++){
    int l = tid + i*256;          // 0..1023
    int o = l>>3; int kq4 = (l&7)*4;
    wo[i] = o; wkq[i] = kq4;
    wsh[i] = v14_whi + (size_t)(obase+o)*768 + kq4;
    wsl[i] = v14_wlo + (size_t)(obase+o)*768 + kq4;
  }

  f32x4 acc[2][4];
  #pragma unroll
  for (int mf=0;mf<2;mf++)
    #pragma unroll
    for (int nf=0;nf<4;nf++) acc[mf][nf] = (f32x4){0.f,0.f,0.f,0.f};

  int fr = lane & 15, fg = lane >> 4;
  int koff = fg*8;

  for (int kt=0; kt<768; kt+=32){
    __syncthreads();
    // stage A (im2col + f16 split)
    #pragma unroll
    for (int i=0;i<2;i++){
      int k0 = kt + akq[i];
      int c = k0>>8, rem = k0&255, ky = rem>>4, kx = rem&15;
      float4 v = *(const float4*)(abase[i] + (size_t)c*180224 + ky*704 + kx);
      half4v hv, lv;
      hv.x = (h16)v.x; lv.x = (h16)(v.x - (float)hv.x);
      hv.y = (h16)v.y; lv.y = (h16)(v.y - (float)hv.y);
      hv.z = (h16)v.z; lv.z = (h16)(v.z - (float)hv.z);
      hv.w = (h16)v.w; lv.w = (h16)(v.w - (float)hv.w);
      *(half4v*)&Ah[app[i]*40 + akq[i]] = hv;
      *(half4v*)&Al[app[i]*40 + akq[i]] = lv;
    }
    // stage W (pre-split in global)
    #pragma unroll
    for (int i=0;i<4;i++){
      half4v hv = *(const half4v*)(wsh[i] + kt);
      half4v lv = *(const half4v*)(wsl[i] + kt);
      *(half4v*)&Bh[wo[i]*40 + wkq[i]] = hv;
      *(half4v*)&Bl[wo[i]*40 + wkq[i]] = lv;
    }
    __syncthreads();
    // fragments
    half8v ah[2], al[2], bh[4], bl[4];
    #pragma unroll
    for (int mf=0;mf<2;mf++){
      int row = wr*32 + mf*16 + fr;
      ah[mf] = *(const half8v*)&Ah[row*40 + koff];
      al[mf] = *(const half8v*)&Al[row*40 + koff];
    }
    #pragma unroll
    for (int nf=0;nf<4;nf++){
      int col = wc*64 + nf*16 + fr;
      bh[nf] = *(const half8v*)&Bh[col*40 + koff];
      bl[nf] = *(const half8v*)&Bl[col*40 + koff];
    }
    #pragma unroll
    for (int mf=0;mf<2;mf++)
      #pragma unroll
      for (int nf=0;nf<4;nf++){
        acc[mf][nf] = __builtin_amdgcn_mfma_f32_16x16x32_f16(ah[mf], bh[nf], acc[mf][nf], 0,0,0);
        acc[mf][nf] = __builtin_amdgcn_mfma_f32_16x16x32_f16(ah[mf], bl[nf], acc[mf][nf], 0,0,0);
        acc[mf][nf] = __builtin_amdgcn_mfma_f32_16x16x32_f16(al[mf], bh[nf], acc[mf][nf], 0,0,0);
      }
  }
  // epilogue: BN + ReLU, C layout col=lane&15, row=(lane>>4)*4+j
  #pragma unroll
  for (int nf=0;nf<4;nf++){
    int ch = obase + wc*64 + nf*16 + fr;
    float sc = g1[ch] / sqrtf(v1[ch] + 1e-5f);
    float sh = b1[ch] - m1[ch]*sc;
    float bi = cb[ch];
    #pragma unroll
    for (int mf=0;mf<2;mf++){
      #pragma unroll
      for (int j=0;j<4;j++){
        int p = pbase + wr*32 + mf*16 + fg*4 + j;
        float t = (acc[mf][nf][j] + bi)*sc + sh;
        v11_xbuf[(size_t)p*256 + ch] = t > 0.f ? t : 0.f;
      }
    }
  }
}

// depth head as f16-split MFMA GEMM: y[16896x105] = x[16896x256] * W^T[256x105]
// block = 64 patches, N padded to 112, K=256. 4 waves, wave = 16 rows x 112 cols.
// Fused softmax (first 41) + ctx split.
__global__ __launch_bounds__(256) void depth_v15(const float* db){
  __shared__ h16 Ah[64*40];      //  5,120 B
  __shared__ h16 Al[64*40];      //  5,120 B
  __shared__ h16 Bh[112*40];     //  8,960 B
  __shared__ h16 Bl[112*40];     //  8,960 B
  __shared__ float sy[64*113];   // 28,928 B (stride 113: softmax reads conflict-free)
  int tid = threadIdx.x;
  int lane = tid & 63, wv = tid >> 6;
  int pbase = blockIdx.x*64;
  int fr = lane & 15, fg = lane >> 4;
  int koff = fg*8;

  f32x4 acc[7];
  #pragma unroll
  for (int nf=0;nf<7;nf++) acc[nf] = (f32x4){0.f,0.f,0.f,0.f};

  for (int kt=0; kt<256; kt+=32){
    __syncthreads();
    // stage A from fp32 xbuf with in-flight hi/lo split
    #pragma unroll
    for (int i=0;i<2;i++){
      int l = tid + i*256;            // 0..511
      int pp = l>>3, kq4 = (l&7)*4;
      float4 v = *(const float4*)&v11_xbuf[(size_t)(pbase+pp)*256 + kt + kq4];
      half4v hv, lv;
      hv.x = (h16)v.x; lv.x = (h16)(v.x - (float)hv.x);
      hv.y = (h16)v.y; lv.y = (h16)(v.y - (float)hv.y);
      hv.z = (h16)v.z; lv.z = (h16)(v.z - (float)hv.z);
      hv.w = (h16)v.w; lv.w = (h16)(v.w - (float)hv.w);
      *(half4v*)&Ah[pp*40 + kq4] = hv;
      *(half4v*)&Al[pp*40 + kq4] = lv;
    }
    // stage W (pre-split, padded rows are zero)
    #pragma unroll
    for (int i=0;i<4;i++){
      int l = tid + i*256;            // 0..1023, need 896
      if (l < 896){
        int o = l>>3, kq4 = (l&7)*4;
        *(half4v*)&Bh[o*40 + kq4] = *(const half4v*)&v15_dwhi[o*256 + kt + kq4];
        *(half4v*)&Bl[o*40 + kq4] = *(const half4v*)&v15_dwlo[o*256 + kt + kq4];
      }
    }
    __syncthreads();
    int row = wv*16 + fr;
    half8v ah = *(const half8v*)&Ah[row*40 + koff];
    half8v al = *(const half8v*)&Al[row*40 + koff];
    #pragma unroll
    for (int nf=0;nf<7;nf++){
      int col = nf*16 + fr;
      half8v bh = *(const half8v*)&Bh[col*40 + koff];
      half8v bl = *(const half8v*)&Bl[col*40 + koff];
      acc[nf] = __builtin_amdgcn_mfma_f32_16x16x32_f16(ah, bh, acc[nf], 0,0,0);
      acc[nf] = __builtin_amdgcn_mfma_f32_16x16x32_f16(ah, bl, acc[nf], 0,0,0);
      acc[nf] = __builtin_amdgcn_mfma_f32_16x16x32_f16(al, bh, acc[nf], 0,0,0);
    }
  }
  // y -> LDS with bias; C layout col=lane&15, row=(lane>>4)*4+j
  #pragma unroll
  for (int nf=0;nf<7;nf++){
    int o = nf*16 + fr;
    if (o < 105){
      float bias = db[o];
      #pragma unroll
      for (int j=0;j<4;j++){
        int pp = wv*16 + fg*4 + j;
        sy[pp*113 + o] = acc[nf][j] + bias;
      }
    }
  }
  __syncthreads();
  // softmax over first 41 per patch (64 threads, one per patch)
  if (tid < 64){
    float* y = &sy[tid*113];
    float m = y[0];
    for (int i=1;i<41;i++) m = fmaxf(m, y[i]);
    float s = 0.f;
    for (int i=0;i<41;i++){ float e = expf(y[i]-m); y[i] = e; s += e; }
    float inv = 1.f/s;
    for (int i=0;i<41;i++) y[i] *= inv;
  }
  __syncthreads();
  // write depth + ctx (coalesced)
  for (int l = tid; l < 64*41; l += 256){
    int pp = l/41, dd = l%41;
    v11_depth[(size_t)(pbase+pp)*41 + dd] = sy[pp*113+dd];
  }
  for (int l = tid; l < 64*64; l += 256){
    int pp = l>>6, c = l&63;
    v11_ctx[(size_t)(pbase+pp)*64 + c] = sy[pp*113 + 41 + c];
  }
}

// voxel rank per point + skew-immune LDS histogram + per-point voxel position.
// 1024 points per block (4 per thread), 64KB LDS hist.
__global__ __launch_bounds__(256) void rank_v13(){
  __shared__ int lh[16384];
  int tid = threadIdx.x;
  for (int i = tid; i < 16384; i += 256) lh[i] = 0;
  __syncthreads();
  int base = blockIdx.x*1024;
  int rk[4], lp[4];
  #pragma unroll
  for (int k=0;k<4;k++){
    int idx = base + k*256 + tid;
    rk[k] = -1; lp[k] = 0;
    if (idx < NPTS){
      int im = idx / 28864;
      int r  = idx % 28864;
      int d  = r / 704; int pix = r % 704;
      int h = pix / 44, w = pix % 44;
      const double* g = v11_geom + im*24;
      double fx = (double)w * (703.0/43.0);
      double fy = (double)h * 17.0;
      double fz = 4.0 + (double)d;
      double px = fx - g[18], py = fy - g[19], pz = fz - g[20];
      double q0 = g[0]*px + g[1]*py + g[2]*pz;
      double q1 = g[3]*px + g[4]*py + g[5]*pz;
      double q2 = g[6]*px + g[7]*py + g[8]*pz;
      q0 *= q2; q1 *= q2;
      double o0 = g[9]*q0  + g[10]*q1 + g[11]*q2 + g[21];
      double o1 = g[12]*q0 + g[13]*q1 + g[14]*q2 + g[22];
      double o2 = g[15]*q0 + g[16]*q1 + g[17]*q2 + g[23];
      int cx = (int)((o0 + 51.2)/0.8);
      int cy = (int)((o1 + 51.2)/0.8);
      int cz = (int)((o2 + 10.0)/20.0);
      int rank = cx + cy*128 + cz*16384;
      if (rank >= 0 && rank < 16384){
        rk[k] = rank;
        lp[k] = atomicAdd(&lh[rank], 1);   // position within block's local count
      }
    }
  }
  __syncthreads();
  // flush nonzero bins; lh[bin] becomes this block's global base for that bin
  for (int i = tid; i < 16384; i += 256){
    int h = lh[i];
    if (h) lh[i] = atomicAdd(&v12_cnt[i], h);
  }
  __syncthreads();
  #pragma unroll
  for (int k=0;k<4;k++){
    int idx = base + k*256 + tid;
    if (idx < NPTS){
      v11_ranks[idx] = rk[k];
      if (rk[k] >= 0) v12_pos[idx] = lh[rk[k]] + lp[k];
    }
  }
}

// exclusive scan over 16384 counts -> offsets + total, single block
__global__ __launch_bounds__(256) void scan_v13(){
  __shared__ int part[256];
  int t = threadIdx.x;
  int base = t*64;
  int s = 0;
  for (int i=0;i<64;i++) s += v12_cnt[base+i];
  part[t] = s;
  __syncthreads();
  if (t == 0){
    int run = 0;
    for (int i=0;i<256;i++){ int v = part[i]; part[i] = run; run += v; }
    v12_total = run;
  }
  __syncthreads();
  int run = part[t];
  for (int i=0;i<64;i++){
    v12_off[base+i] = run;
    run += v12_cnt[base+i];
  }
}

// place points into rank-sorted order — NO atomics (position precomputed)
__global__ __launch_bounds__(256) void fill_v13(){
  int idx = blockIdx.x*256 + threadIdx.x;
  if (idx >= NPTS) return;
  int rank = v11_ranks[idx];
  if (rank < 0) return;
  int im = idx / 28864;
  int r  = idx % 28864;
  int d  = r / 704; int pix = r % 704;
  int p  = im*704 + pix;
  int pos = v12_off[rank] + v12_pos[idx];
  v12_sorted[pos] = make_int2((p<<6) | d, rank);
}

// work-balanced segmented reduction: one wave per 64 sorted points, lane = channel.
// Register-accumulate runs of equal rank; atomic flush only at rank transitions.
__global__ __launch_bounds__(256) void gather_v13(){
  int total = v12_total;
  int w = threadIdx.x >> 6;
  int chunk = blockIdx.x*256 + w*64;
  if (chunk >= total) return;
  int lane = threadIdx.x & 63;
  int n = total - chunk; if (n > 64) n = 64;
  // per-lane coalesced load of one point (packed, rank) + its depth weight
  int pv = 0, rv = -1;
  float dv = 0.f;
  if (lane < n){
    int2 sr = v12_sorted[chunk + lane];
    pv = sr.x; rv = sr.y;
    dv = v11_depth[(pv>>6)*41 + (pv & 63)];
  }
  float acc = 0.f;
  int cur = __shfl(rv, 0);
  for (int i = 0; i < n; i++){
    int rk = __shfl(rv, i);
    int pp = __shfl(pv, i) >> 6;
    float dd = __shfl(dv, i);
    if (rk != cur){                       // wave-uniform branch
      atomicAdd(&v11_bev[(size_t)cur*64 + lane], acc);
      acc = 0.f; cur = rk;
    }
    acc += v11_ctx[(pp<<6) | lane] * dd;  // coalesced 256B row read
  }
  atomicAdd(&v11_bev[(size_t)cur*64 + lane], acc);
}

// bev output: [yx][c] -> out1[c][y][x] fp32
__global__ void bevout_v11(float* out1){
  int gid = blockIdx.x*256 + threadIdx.x;
  int c  = gid >> 14;
  int yx = gid & 16383;
  out1[gid] = v11_bev[(size_t)yx*64 + c];
}

// fold enc_w concat([bev,bev]) halves
__global__ void w2_v11(const float* enc_w){
  int gid = blockIdx.x*256 + threadIdx.x;
  if (gid >= 36864) return;
  int o = gid / 576; int rem = gid % 576;
  int ic = rem / 9, t = rem % 9;
  v11_w2[gid] = enc_w[o*1152 + ic*9 + t] + enc_w[o*1152 + (ic+64)*9 + t];
}

// conv2 3x3 SAME + BN2 + ReLU + 7x64 head, fused
__global__ __launch_bounds__(256) void conv2_v11(
    const float* eb, const float* g2, const float* b2_, const float* m2, const float* v2,
    const float* hw, const float* hb, float* out0){
  __shared__ float itile[64*100];     // 25,600 B
  __shared__ float wtile[64*72];      // 18,432 B
  __shared__ float hred[4*64*7];      //  7,168 B
  int tid = threadIdx.x;
  int og  = tid >> 6;
  int pix = tid & 63;
  int py = pix >> 3, px = pix & 7;
  int by = blockIdx.y, bx = blockIdx.x;
  for (int l = tid; l < 6400; l += 256){
    int ic = l / 100, rem = l % 100;
    int iy = rem / 10, ix = rem % 10;
    int gy = by*8 + iy - 1, gx = bx*8 + ix - 1;
    itile[l] = (gy>=0 && gy<128 && gx>=0 && gx<128) ? v11_bev[(size_t)(gy*128+gx)*64 + ic] : 0.f;
  }
  float acc[16];
  #pragma unroll
  for (int j=0;j<16;j++) acc[j]=0.f;
  for (int it=0; it<64; it+=8){
    __syncthreads();
    for (int l = tid; l < 64*72; l += 256){
      int oc = l / 72, rem = l % 72;
      wtile[l] = v11_w2[oc*576 + it*9 + rem];
    }
    __syncthreads();
    for (int icl=0; icl<8; icl++){
      int ic = it + icl;
      const float* ibase = itile + ic*100 + py*10 + px;
      float iv[9];
      #pragma unroll
      for (int t=0;t<9;t++) iv[t] = ibase[(t/3)*10 + (t%3)];
      const float* wbase = wtile + (og*16)*72 + icl*9;
      #pragma unroll
      for (int j=0;j<16;j++){
        #pragma unroll
        for (int t=0;t<9;t++) acc[j] += iv[t]*wbase[j*72+t];
      }
    }
  }
  float part[7];
  #pragma unroll
  for (int o=0;o<7;o++) part[o]=0.f;
  for (int j=0;j<16;j++){
    int oc = og*16+j;
    float scale = g2[oc]/sqrtf(v2[oc]+1e-5f);
    float shift = b2_[oc] - m2[oc]*scale;
    float v = (acc[j] + eb[oc])*scale + shift;
    v = v > 0.f ? v : 0.f;
    #pragma unroll
    for (int o=0;o<7;o++) part[o] += hw[o*64+oc]*v;
  }
  __syncthreads();
  for (int o=0;o<7;o++) hred[(og*64+pix)*7+o] = part[o];
  __syncthreads();
  if (og == 0){
    int gy = by*8+py, gx = bx*8+px;
    for (int o=0;o<7;o++){
      float s = hred[pix*7+o] + hred[(64+pix)*7+o] + hred[(128+pix)*7+o]
              + hred[(192+pix)*7+o] + hb[o];
      out0[o*16384 + gy*128 + gx] = s;
    }
  }
}

extern "C" void kernel_launch(void* const* d_in, const int* in_sizes, int n_in,
                              void* d_out, int out_size, void* d_ws, size_t ws_size,
                              hipStream_t stream){
  const float* imgs       = (const float*)d_in[0];
  const float* rots       = (const float*)d_in[1];
  const float* trans      = (const float*)d_in[2];
  const float* intrins    = (const float*)d_in[3];
  const float* post_rots  = (const float*)d_in[4];
  const float* post_trans = (const float*)d_in[5];
  const float* conv_w     = (const float*)d_in[6];
  const float* conv_b     = (const float*)d_in[7];
  const float* bn1_g      = (const float*)d_in[8];
  const float* bn1_b      = (const float*)d_in[9];
  const float* bn1_m      = (const float*)d_in[10];
  const float* bn1_v      = (const float*)d_in[11];
  const float* depth_w    = (const float*)d_in[12];
  const float* depth_b    = (const float*)d_in[13];
  const float* enc_w      = (const float*)d_in[14];
  const float* enc_b      = (const float*)d_in[15];
  const float* bn2_g      = (const float*)d_in[16];
  const float* bn2_b      = (const float*)d_in[17];
  const float* bn2_m      = (const float*)d_in[18];
  const float* bn2_v      = (const float*)d_in[19];
  const float* head_w     = (const float*)d_in[20];
  const float* head_b     = (const float*)d_in[21];

  float* out0 = (float*)d_out;          // (1,7,128,128)
  float* out1 = out0 + 114688;          // (1,64,128,128)

  zero_v13<<<4096, 256, 0, stream>>>();
  geom_v11<<<1, 32, 0, stream>>>(rots, trans, intrins, post_rots, post_trans);
  wt_v14<<<768, 256, 0, stream>>>(conv_w);
  wtd_v15<<<112, 256, 0, stream>>>(depth_w);
  conv1_v14<<<dim3(264, 2), 256, 0, stream>>>(imgs, conv_b, bn1_g, bn1_b, bn1_m, bn1_v);
  depth_v15<<<264, 256, 0, stream>>>(depth_b);
  rank_v13<<<(NPTS+1023)/1024, 256, 0, stream>>>();
  scan_v13<<<1, 256, 0, stream>>>();
  fill_v13<<<NPTS/256, 256, 0, stream>>>();
  gather_v13<<<NPTS/256, 256, 0, stream>>>();
  w2_v11<<<144, 256, 0, stream>>>(enc_w);
  bevout_v11<<<4096, 256, 0, stream>>>(out1);
  conv2_v11<<<dim3(16,16), 256, 0, stream>>>(enc_b, bn2_g, bn2_b, bn2_m, bn2_v,
                                             head_w, head_b, out0);
}

// Round 5
// 286.319 us; speedup vs baseline: 3.9593x; 1.2187x over previous
//
#include <hip/hip_runtime.h>
#include <hip/hip_bf16.h>
#include <hip/hip_fp16.h>

#define NPTS 692736      // 24*41*16*44
#define NPATCH 16896     // 24*16*44

typedef _Float16 h16;
typedef __attribute__((ext_vector_type(4))) _Float16 half4v;
typedef __attribute__((ext_vector_type(8))) _Float16 half8v;
typedef __attribute__((ext_vector_type(4))) float f32x4;

// ---------- module-scope device globals ----------
__device__ float  v11_xbuf[NPATCH*256];
__device__ float  v11_ctx[NPATCH*64];
__device__ float  v11_depth[NPATCH*41];
__device__ int    v11_ranks[NPTS];
__device__ float  v11_bev[16384*64];
__device__ double v11_geom[24*24];

// f16 hi/lo split conv1 weights, [o][k] flat (o*768+k)
__device__ h16    v14_whi[256*768];
__device__ h16    v14_wlo[256*768];

// f16 hi/lo split depth weights, padded [112][256] ([o][c])
__device__ h16    v15_dwhi[112*256];
__device__ h16    v15_dwlo[112*256];

// f16 hi/lo split folded conv2 weights, [o][k] with k = tap*64 + ic
__device__ h16    v16_w2hi[64*576];
__device__ h16    v16_w2lo[64*576];

// counting-sort state for scatter->gather inversion
__device__ int    v12_cnt[16384];
__device__ int    v12_off[16384];
__device__ int    v12_pos[NPTS];       // position within own voxel
__device__ int2   v12_sorted[NPTS];    // (packed (p<<6)|d, rank) in rank order
__device__ int    v12_total;

__device__ __forceinline__ void inv3_v11(const double* m, double* o){
  double a=m[0],b=m[1],c=m[2],d=m[3],e=m[4],f=m[5],g=m[6],h=m[7],i=m[8];
  double A = e*i - f*h, B = -(d*i - f*g), C = d*h - e*g;
  double det = a*A + b*B + c*C;
  double id = 1.0/det;
  o[0]=A*id;            o[1]=-(b*i - c*h)*id; o[2]=(b*f - c*e)*id;
  o[3]=B*id;            o[4]=(a*i - c*g)*id;  o[5]=-(a*f - c*d)*id;
  o[6]=C*id;            o[7]=-(a*h - b*g)*id; o[8]=(a*e - b*d)*id;
}

// zero bev accumulator + histogram counts
__global__ void zero_v13(){
  int gid = blockIdx.x*256 + threadIdx.x;   // 1,048,576
  v11_bev[gid] = 0.f;
  if (gid < 16384) v12_cnt[gid] = 0;
}

__global__ void geom_v11(const float* rots, const float* trans, const float* intrins,
                         const float* post_rots, const float* post_trans){
  int t = threadIdx.x;
  if (t >= 24) return;
  double pr[9], it[9], r[9];
  for (int i=0;i<9;i++){
    pr[i] = (double)post_rots[t*9+i];
    it[i] = (double)intrins[t*9+i];
    r[i]  = (double)rots[t*9+i];
  }
  double ipr[9], iit[9];
  inv3_v11(pr, ipr); inv3_v11(it, iit);
  double* g = v11_geom + t*24;
  for (int i=0;i<3;i++) for(int j=0;j<3;j++){
    double s=0; for(int k=0;k<3;k++) s += r[i*3+k]*iit[k*3+j];
    g[9+i*3+j]=s;
  }
  for (int i=0;i<9;i++) g[i]   = ipr[i];
  for (int i=0;i<3;i++) g[18+i]= (double)post_trans[t*3+i];
  for (int i=0;i<3;i++) g[21+i]= (double)trans[t*3+i];
}

// split conv_w into f16 hi/lo, layout [o][k] (same flat order as conv_w)
__global__ void wt_v14(const float* cw){
  int gid = blockIdx.x*256 + threadIdx.x;   // 196608
  float x = cw[gid];
  h16 hi = (h16)x;
  h16 lo = (h16)(x - (float)hi);
  v14_whi[gid] = hi;
  v14_wlo[gid] = lo;
}

// split depth_w [105][256] into f16 hi/lo padded to [112][256]
__global__ void wtd_v15(const float* dw){
  int gid = blockIdx.x*256 + threadIdx.x;   // 28672
  int o = gid >> 8, c = gid & 255;
  float x = (o < 105) ? dw[o*256 + c] : 0.f;
  h16 hi = (h16)x;
  h16 lo = (h16)(x - (float)hi);
  v15_dwhi[gid] = hi;
  v15_dwlo[gid] = lo;
}

// fold enc_w concat([bev,bev]) halves + f16 hi/lo split, k-order = tap*64+ic
__global__ void w2_v16(const float* enc_w){
  int gid = blockIdx.x*256 + threadIdx.x;
  if (gid >= 36864) return;
  int o = gid / 576; int k = gid % 576;
  int tap = k >> 6, ic = k & 63;
  float x = enc_w[o*1152 + ic*9 + tap] + enc_w[o*1152 + (ic+64)*9 + tap];
  h16 hi = (h16)x;
  h16 lo = (h16)(x - (float)hi);
  v16_w2hi[gid] = hi;
  v16_w2lo[gid] = lo;
}

// conv1 as f16-split MFMA GEMM: C[16896x256] = A[16896x768] * W[768x256]
// block tile 64(M) x 128(N) x 32(K), 4 waves, wave sub-tile 32x64.
// A,B LDS layout: [row][k] with row stride 40 halves (80B: bank-spread, 16B-aligned)
__global__ __launch_bounds__(256) void conv1_v14(const float* img,
    const float* cb, const float* g1, const float* b1, const float* m1, const float* v1){
  __shared__ h16 Ah[64*40];
  __shared__ h16 Al[64*40];
  __shared__ h16 Bh[128*40];
  __shared__ h16 Bl[128*40];
  int tid  = threadIdx.x;
  int lane = tid & 63, wv = tid >> 6;
  int wr = wv >> 1, wc = wv & 1;          // wave grid 2(M) x 2(N)
  int pbase = blockIdx.x * 64;
  int obase = blockIdx.y * 128;

  // --- A staging descriptors (2 float4-quads/thread/K-step), hoisted ---
  const float* abase[2];
  int app[2], akq[2];
  #pragma unroll
  for (int i=0;i<2;i++){
    int l = tid + i*256;          // 0..511
    int pp = l>>3; int kq4 = (l&7)*4;
    app[i] = pp; akq[i] = kq4;
    int p = pbase + pp;
    int im = p/704; int pix = p%704;
    int ph = pix/44, pw = pix%44;
    abase[i] = img + (size_t)im*540672 + (size_t)ph*16*704 + pw*16;
  }
  // --- W staging descriptors (4 half4-quads/thread/K-step per array) ---
  const h16* wsh[4]; const h16* wsl[4];
  int wo[4], wkq[4];
  #pragma unroll
  for (int i=0;i<4;i++){
    int l = tid + i*256;          // 0..1023
    int o = l>>3; int kq4 = (l&7)*4;
    wo[i] = o; wkq[i] = kq4;
    wsh[i] = v14_whi + (size_t)(obase+o)*768 + kq4;
    wsl[i] = v14_wlo + (size_t)(obase+o)*768 + kq4;
  }

  f32x4 acc[2][4];
  #pragma unroll
  for (int mf=0;mf<2;mf++)
    #pragma unroll
    for (int nf=0;nf<4;nf++) acc[mf][nf] = (f32x4){0.f,0.f,0.f,0.f};

  int fr = lane & 15, fg = lane >> 4;
  int koff = fg*8;

  for (int kt=0; kt<768; kt+=32){
    __syncthreads();
    // stage A (im2col + f16 split)
    #pragma unroll
    for (int i=0;i<2;i++){
      int k0 = kt + akq[i];
      int c = k0>>8, rem = k0&255, ky = rem>>4, kx = rem&15;
      float4 v = *(const float4*)(abase[i] + (size_t)c*180224 + ky*704 + kx);
      half4v hv, lv;
      hv.x = (h16)v.x; lv.x = (h16)(v.x - (float)hv.x);
      hv.y = (h16)v.y; lv.y = (h16)(v.y - (float)hv.y);
      hv.z = (h16)v.z; lv.z = (h16)(v.z - (float)hv.z);
      hv.w = (h16)v.w; lv.w = (h16)(v.w - (float)hv.w);
      *(half4v*)&Ah[app[i]*40 + akq[i]] = hv;
      *(half4v*)&Al[app[i]*40 + akq[i]] = lv;
    }
    // stage W (pre-split in global)
    #pragma unroll
    for (int i=0;i<4;i++){
      half4v hv = *(const half4v*)(wsh[i] + kt);
      half4v lv = *(const half4v*)(wsl[i] + kt);
      *(half4v*)&Bh[wo[i]*40 + wkq[i]] = hv;
      *(half4v*)&Bl[wo[i]*40 + wkq[i]] = lv;
    }
    __syncthreads();
    // fragments
    half8v ah[2], al[2], bh[4], bl[4];
    #pragma unroll
    for (int mf=0;mf<2;mf++){
      int row = wr*32 + mf*16 + fr;
      ah[mf] = *(const half8v*)&Ah[row*40 + koff];
      al[mf] = *(const half8v*)&Al[row*40 + koff];
    }
    #pragma unroll
    for (int nf=0;nf<4;nf++){
      int col = wc*64 + nf*16 + fr;
      bh[nf] = *(const half8v*)&Bh[col*40 + koff];
      bl[nf] = *(const half8v*)&Bl[col*40 + koff];
    }
    #pragma unroll
    for (int mf=0;mf<2;mf++)
      #pragma unroll
      for (int nf=0;nf<4;nf++){
        acc[mf][nf] = __builtin_amdgcn_mfma_f32_16x16x32_f16(ah[mf], bh[nf], acc[mf][nf], 0,0,0);
        acc[mf][nf] = __builtin_amdgcn_mfma_f32_16x16x32_f16(ah[mf], bl[nf], acc[mf][nf], 0,0,0);
        acc[mf][nf] = __builtin_amdgcn_mfma_f32_16x16x32_f16(al[mf], bh[nf], acc[mf][nf], 0,0,0);
      }
  }
  // epilogue: BN + ReLU, C layout col=lane&15, row=(lane>>4)*4+j
  #pragma unroll
  for (int nf=0;nf<4;nf++){
    int ch = obase + wc*64 + nf*16 + fr;
    float sc = g1[ch] / sqrtf(v1[ch] + 1e-5f);
    float sh = b1[ch] - m1[ch]*sc;
    float bi = cb[ch];
    #pragma unroll
    for (int mf=0;mf<2;mf++){
      #pragma unroll
      for (int j=0;j<4;j++){
        int p = pbase + wr*32 + mf*16 + fg*4 + j;
        float t = (acc[mf][nf][j] + bi)*sc + sh;
        v11_xbuf[(size_t)p*256 + ch] = t > 0.f ? t : 0.f;
      }
    }
  }
}

// depth head as f16-split MFMA GEMM: y[16896x105] = x[16896x256] * W^T[256x105]
// block = 64 patches, N padded to 112, K=256. 4 waves, wave = 16 rows x 112 cols.
// Fused softmax (first 41) + ctx split.
__global__ __launch_bounds__(256) void depth_v15(const float* db){
  __shared__ h16 Ah[64*40];      //  5,120 B
  __shared__ h16 Al[64*40];      //  5,120 B
  __shared__ h16 Bh[112*40];     //  8,960 B
  __shared__ h16 Bl[112*40];     //  8,960 B
  __shared__ float sy[64*113];   // 28,928 B (stride 113: softmax reads conflict-free)
  int tid = threadIdx.x;
  int lane = tid & 63, wv = tid >> 6;
  int pbase = blockIdx.x*64;
  int fr = lane & 15, fg = lane >> 4;
  int koff = fg*8;

  f32x4 acc[7];
  #pragma unroll
  for (int nf=0;nf<7;nf++) acc[nf] = (f32x4){0.f,0.f,0.f,0.f};

  for (int kt=0; kt<256; kt+=32){
    __syncthreads();
    // stage A from fp32 xbuf with in-flight hi/lo split
    #pragma unroll
    for (int i=0;i<2;i++){
      int l = tid + i*256;            // 0..511
      int pp = l>>3, kq4 = (l&7)*4;
      float4 v = *(const float4*)&v11_xbuf[(size_t)(pbase+pp)*256 + kt + kq4];
      half4v hv, lv;
      hv.x = (h16)v.x; lv.x = (h16)(v.x - (float)hv.x);
      hv.y = (h16)v.y; lv.y = (h16)(v.y - (float)hv.y);
      hv.z = (h16)v.z; lv.z = (h16)(v.z - (float)hv.z);
      hv.w = (h16)v.w; lv.w = (h16)(v.w - (float)hv.w);
      *(half4v*)&Ah[pp*40 + kq4] = hv;
      *(half4v*)&Al[pp*40 + kq4] = lv;
    }
    // stage W (pre-split, padded rows are zero)
    #pragma unroll
    for (int i=0;i<4;i++){
      int l = tid + i*256;            // 0..1023, need 896
      if (l < 896){
        int o = l>>3, kq4 = (l&7)*4;
        *(half4v*)&Bh[o*40 + kq4] = *(const half4v*)&v15_dwhi[o*256 + kt + kq4];
        *(half4v*)&Bl[o*40 + kq4] = *(const half4v*)&v15_dwlo[o*256 + kt + kq4];
      }
    }
    __syncthreads();
    int row = wv*16 + fr;
    half8v ah = *(const half8v*)&Ah[row*40 + koff];
    half8v al = *(const half8v*)&Al[row*40 + koff];
    #pragma unroll
    for (int nf=0;nf<7;nf++){
      int col = nf*16 + fr;
      half8v bh = *(const half8v*)&Bh[col*40 + koff];
      half8v bl = *(const half8v*)&Bl[col*40 + koff];
      acc[nf] = __builtin_amdgcn_mfma_f32_16x16x32_f16(ah, bh, acc[nf], 0,0,0);
      acc[nf] = __builtin_amdgcn_mfma_f32_16x16x32_f16(ah, bl, acc[nf], 0,0,0);
      acc[nf] = __builtin_amdgcn_mfma_f32_16x16x32_f16(al, bh, acc[nf], 0,0,0);
    }
  }
  // y -> LDS with bias; C layout col=lane&15, row=(lane>>4)*4+j
  #pragma unroll
  for (int nf=0;nf<7;nf++){
    int o = nf*16 + fr;
    if (o < 105){
      float bias = db[o];
      #pragma unroll
      for (int j=0;j<4;j++){
        int pp = wv*16 + fg*4 + j;
        sy[pp*113 + o] = acc[nf][j] + bias;
      }
    }
  }
  __syncthreads();
  // softmax over first 41 per patch (64 threads, one per patch)
  if (tid < 64){
    float* y = &sy[tid*113];
    float m = y[0];
    for (int i=1;i<41;i++) m = fmaxf(m, y[i]);
    float s = 0.f;
    for (int i=0;i<41;i++){ float e = expf(y[i]-m); y[i] = e; s += e; }
    float inv = 1.f/s;
    for (int i=0;i<41;i++) y[i] *= inv;
  }
  __syncthreads();
  // write depth + ctx (coalesced)
  for (int l = tid; l < 64*41; l += 256){
    int pp = l/41, dd = l%41;
    v11_depth[(size_t)(pbase+pp)*41 + dd] = sy[pp*113+dd];
  }
  for (int l = tid; l < 64*64; l += 256){
    int pp = l>>6, c = l&63;
    v11_ctx[(size_t)(pbase+pp)*64 + c] = sy[pp*113 + 41 + c];
  }
}

// voxel rank per point + skew-immune LDS histogram + per-point voxel position.
// 1024 points per block (4 per thread), 64KB LDS hist.
__global__ __launch_bounds__(256) void rank_v13(){
  __shared__ int lh[16384];
  int tid = threadIdx.x;
  for (int i = tid; i < 16384; i += 256) lh[i] = 0;
  __syncthreads();
  int base = blockIdx.x*1024;
  int rk[4], lp[4];
  #pragma unroll
  for (int k=0;k<4;k++){
    int idx = base + k*256 + tid;
    rk[k] = -1; lp[k] = 0;
    if (idx < NPTS){
      int im = idx / 28864;
      int r  = idx % 28864;
      int d  = r / 704; int pix = r % 704;
      int h = pix / 44, w = pix % 44;
      const double* g = v11_geom + im*24;
      double fx = (double)w * (703.0/43.0);
      double fy = (double)h * 17.0;
      double fz = 4.0 + (double)d;
      double px = fx - g[18], py = fy - g[19], pz = fz - g[20];
      double q0 = g[0]*px + g[1]*py + g[2]*pz;
      double q1 = g[3]*px + g[4]*py + g[5]*pz;
      double q2 = g[6]*px + g[7]*py + g[8]*pz;
      q0 *= q2; q1 *= q2;
      double o0 = g[9]*q0  + g[10]*q1 + g[11]*q2 + g[21];
      double o1 = g[12]*q0 + g[13]*q1 + g[14]*q2 + g[22];
      double o2 = g[15]*q0 + g[16]*q1 + g[17]*q2 + g[23];
      int cx = (int)((o0 + 51.2)/0.8);
      int cy = (int)((o1 + 51.2)/0.8);
      int cz = (int)((o2 + 10.0)/20.0);
      int rank = cx + cy*128 + cz*16384;
      if (rank >= 0 && rank < 16384){
        rk[k] = rank;
        lp[k] = atomicAdd(&lh[rank], 1);   // position within block's local count
      }
    }
  }
  __syncthreads();
  // flush nonzero bins; lh[bin] becomes this block's global base for that bin
  for (int i = tid; i < 16384; i += 256){
    int h = lh[i];
    if (h) lh[i] = atomicAdd(&v12_cnt[i], h);
  }
  __syncthreads();
  #pragma unroll
  for (int k=0;k<4;k++){
    int idx = base + k*256 + tid;
    if (idx < NPTS){
      v11_ranks[idx] = rk[k];
      if (rk[k] >= 0) v12_pos[idx] = lh[rk[k]] + lp[k];
    }
  }
}

// exclusive scan over 16384 counts -> offsets + total, single block
__global__ __launch_bounds__(256) void scan_v13(){
  __shared__ int part[256];
  int t = threadIdx.x;
  int base = t*64;
  int s = 0;
  for (int i=0;i<64;i++) s += v12_cnt[base+i];
  part[t] = s;
  __syncthreads();
  if (t == 0){
    int run = 0;
    for (int i=0;i<256;i++){ int v = part[i]; part[i] = run; run += v; }
    v12_total = run;
  }
  __syncthreads();
  int run = part[t];
  for (int i=0;i<64;i++){
    v12_off[base+i] = run;
    run += v12_cnt[base+i];
  }
}

// place points into rank-sorted order — NO atomics (position precomputed)
__global__ __launch_bounds__(256) void fill_v13(){
  int idx = blockIdx.x*256 + threadIdx.x;
  if (idx >= NPTS) return;
  int rank = v11_ranks[idx];
  if (rank < 0) return;
  int im = idx / 28864;
  int r  = idx % 28864;
  int d  = r / 704; int pix = r % 704;
  int p  = im*704 + pix;
  int pos = v12_off[rank] + v12_pos[idx];
  v12_sorted[pos] = make_int2((p<<6) | d, rank);
}

// work-balanced segmented reduction: one wave per 64 sorted points, lane = channel.
// Register-accumulate runs of equal rank; atomic flush only at rank transitions.
__global__ __launch_bounds__(256) void gather_v13(){
  int total = v12_total;
  int w = threadIdx.x >> 6;
  int chunk = blockIdx.x*256 + w*64;
  if (chunk >= total) return;
  int lane = threadIdx.x & 63;
  int n = total - chunk; if (n > 64) n = 64;
  // per-lane coalesced load of one point (packed, rank) + its depth weight
  int pv = 0, rv = -1;
  float dv = 0.f;
  if (lane < n){
    int2 sr = v12_sorted[chunk + lane];
    pv = sr.x; rv = sr.y;
    dv = v11_depth[(pv>>6)*41 + (pv & 63)];
  }
  float acc = 0.f;
  int cur = __shfl(rv, 0);
  for (int i = 0; i < n; i++){
    int rk = __shfl(rv, i);
    int pp = __shfl(pv, i) >> 6;
    float dd = __shfl(dv, i);
    if (rk != cur){                       // wave-uniform branch
      atomicAdd(&v11_bev[(size_t)cur*64 + lane], acc);
      acc = 0.f; cur = rk;
    }
    acc += v11_ctx[(pp<<6) | lane] * dd;  // coalesced 256B row read
  }
  atomicAdd(&v11_bev[(size_t)cur*64 + lane], acc);
}

// bev output: [yx][c] -> out1[c][y][x] fp32
__global__ void bevout_v11(float* out1){
  int gid = blockIdx.x*256 + threadIdx.x;
  int c  = gid >> 14;
  int yx = gid & 16383;
  out1[gid] = v11_bev[(size_t)yx*64 + c];
}

// conv2 3x3 SAME as f16-split implicit-GEMM MFMA + BN2 + ReLU + 7x64 head.
// Block = 8x8 pixel tile (M=64) x N=64, K=576 (tap*64+ic), staged from L2-resident bev.
__global__ __launch_bounds__(256) void conv2_v16(
    const float* eb, const float* g2, const float* b2_, const float* m2, const float* v2,
    const float* hw, const float* hb, float* out0){
  __shared__ h16 Ah[64*40];      //  5,120 B
  __shared__ h16 Al[64*40];
  __shared__ h16 Bh[64*40];
  __shared__ h16 Bl[64*40];
  __shared__ float sfeat[64*68]; // 17,408 B
  __shared__ float hred[4*64*7]; //  7,168 B
  int tid = threadIdx.x;
  int lane = tid & 63, wv = tid >> 6;
  int bx = blockIdx.x & 15, by = blockIdx.x >> 4;
  int fr = lane & 15, fg = lane >> 4;
  int koff = fg*8;

  f32x4 acc[4];
  #pragma unroll
  for (int nf=0;nf<4;nf++) acc[nf] = (f32x4){0.f,0.f,0.f,0.f};

  for (int kt=0; kt<576; kt+=32){
    int tap = kt >> 6, ic0 = kt & 32;
    int dy = tap/3 - 1, dx = tap%3 - 1;
    __syncthreads();
    // stage A: 64 pixels x 32 ch from bev (boundary-zero), hi/lo split in flight
    #pragma unroll
    for (int i=0;i<2;i++){
      int l = tid + i*256;          // 0..511
      int pp = l>>3, q4 = (l&7)*4;
      int py = pp>>3, px = pp&7;
      int gy = by*8 + py + dy, gx = bx*8 + px + dx;
      float4 v = {0.f,0.f,0.f,0.f};
      if (gy>=0 && gy<128 && gx>=0 && gx<128)
        v = *(const float4*)&v11_bev[(size_t)(gy*128+gx)*64 + ic0 + q4];
      half4v hv, lv;
      hv.x = (h16)v.x; lv.x = (h16)(v.x - (float)hv.x);
      hv.y = (h16)v.y; lv.y = (h16)(v.y - (float)hv.y);
      hv.z = (h16)v.z; lv.z = (h16)(v.z - (float)hv.z);
      hv.w = (h16)v.w; lv.w = (h16)(v.w - (float)hv.w);
      *(half4v*)&Ah[pp*40 + q4] = hv;
      *(half4v*)&Al[pp*40 + q4] = lv;
    }
    // stage W (pre-split, k-order matches)
    #pragma unroll
    for (int i=0;i<2;i++){
      int l = tid + i*256;          // 0..511
      int o = l>>3, q4 = (l&7)*4;
      *(half4v*)&Bh[o*40 + q4] = *(const half4v*)&v16_w2hi[o*576 + kt + q4];
      *(half4v*)&Bl[o*40 + q4] = *(const half4v*)&v16_w2lo[o*576 + kt + q4];
    }
    __syncthreads();
    int row = wv*16 + fr;
    half8v ah = *(const half8v*)&Ah[row*40 + koff];
    half8v al = *(const half8v*)&Al[row*40 + koff];
    #pragma unroll
    for (int nf=0;nf<4;nf++){
      int col = nf*16 + fr;
      half8v bh = *(const half8v*)&Bh[col*40 + koff];
      half8v bl = *(const half8v*)&Bl[col*40 + koff];
      acc[nf] = __builtin_amdgcn_mfma_f32_16x16x32_f16(ah, bh, acc[nf], 0,0,0);
      acc[nf] = __builtin_amdgcn_mfma_f32_16x16x32_f16(ah, bl, acc[nf], 0,0,0);
      acc[nf] = __builtin_amdgcn_mfma_f32_16x16x32_f16(al, bh, acc[nf], 0,0,0);
    }
  }
  // BN + ReLU -> sfeat; C layout col=lane&15, row=(lane>>4)*4+j
  #pragma unroll
  for (int nf=0;nf<4;nf++){
    int ch = nf*16 + fr;
    float sc = g2[ch]/sqrtf(v2[ch]+1e-5f);
    float sh = b2_[ch] - m2[ch]*sc;
    float bi = eb[ch];
    #pragma unroll
    for (int j=0;j<4;j++){
      int pp = wv*16 + fg*4 + j;
      float t = (acc[nf][j] + bi)*sc + sh;
      sfeat[pp*68 + ch] = t > 0.f ? t : 0.f;
    }
  }
  __syncthreads();
  // head: 7x64, partial over 16 channels per og, LDS reduce
  int og = tid >> 6, pix = tid & 63;
  float part[7];
  #pragma unroll
  for (int o=0;o<7;o++) part[o]=0.f;
  #pragma unroll
  for (int j=0;j<16;j++){
    int oc = og*16 + j;
    float v = sfeat[pix*68 + oc];
    #pragma unroll
    for (int o=0;o<7;o++) part[o] += hw[o*64+oc]*v;
  }
  #pragma unroll
  for (int o=0;o<7;o++) hred[(og*64+pix)*7+o] = part[o];
  __syncthreads();
  if (og == 0){
    int gy = by*8 + (pix>>3), gx = bx*8 + (pix&7);
    #pragma unroll
    for (int o=0;o<7;o++){
      float s = hred[pix*7+o] + hred[(64+pix)*7+o] + hred[(128+pix)*7+o]
              + hred[(192+pix)*7+o] + hb[o];
      out0[o*16384 + gy*128 + gx] = s;
    }
  }
}

extern "C" void kernel_launch(void* const* d_in, const int* in_sizes, int n_in,
                              void* d_out, int out_size, void* d_ws, size_t ws_size,
                              hipStream_t stream){
  const float* imgs       = (const float*)d_in[0];
  const float* rots       = (const float*)d_in[1];
  const float* trans      = (const float*)d_in[2];
  const float* intrins    = (const float*)d_in[3];
  const float* post_rots  = (const float*)d_in[4];
  const float* post_trans = (const float*)d_in[5];
  const float* conv_w     = (const float*)d_in[6];
  const float* conv_b     = (const float*)d_in[7];
  const float* bn1_g      = (const float*)d_in[8];
  const float* bn1_b      = (const float*)d_in[9];
  const float* bn1_m      = (const float*)d_in[10];
  const float* bn1_v      = (const float*)d_in[11];
  const float* depth_w    = (const float*)d_in[12];
  const float* depth_b    = (const float*)d_in[13];
  const float* enc_w      = (const float*)d_in[14];
  const float* enc_b      = (const float*)d_in[15];
  const float* bn2_g      = (const float*)d_in[16];
  const float* bn2_b      = (const float*)d_in[17];
  const float* bn2_m      = (const float*)d_in[18];
  const float* bn2_v      = (const float*)d_in[19];
  const float* head_w     = (const float*)d_in[20];
  const float* head_b     = (const float*)d_in[21];

  float* out0 = (float*)d_out;          // (1,7,128,128)
  float* out1 = out0 + 114688;          // (1,64,128,128)

  zero_v13<<<4096, 256, 0, stream>>>();
  geom_v11<<<1, 32, 0, stream>>>(rots, trans, intrins, post_rots, post_trans);
  wt_v14<<<768, 256, 0, stream>>>(conv_w);
  wtd_v15<<<112, 256, 0, stream>>>(depth_w);
  w2_v16<<<144, 256, 0, stream>>>(enc_w);
  conv1_v14<<<dim3(264, 2), 256, 0, stream>>>(imgs, conv_b, bn1_g, bn1_b, bn1_m, bn1_v);
  depth_v15<<<264, 256, 0, stream>>>(depth_b);
  rank_v13<<<(NPTS+1023)/1024, 256, 0, stream>>>();
  scan_v13<<<1, 256, 0, stream>>>();
  fill_v13<<<NPTS/256, 256, 0, stream>>>();
  gather_v13<<<NPTS/256, 256, 0, stream>>>();
  bevout_v11<<<4096, 256, 0, stream>>>(out1);
  conv2_v16<<<256, 256, 0, stream>>>(enc_b, bn2_g, bn2_b, bn2_m, bn2_v,
                                     head_w, head_b, out0);
}